// Round 8
// baseline (3158.101 us; speedup 1.0000x reference)
//
#include <hip/hip_runtime.h>

typedef unsigned int u32;

constexpr int BATCH = 8;
constexpr int GH = 32, GW = 64;
constexpr int FH = 128, FW = 512;
constexpr int NFFT = 1024;
constexpr int HOP = 256;
constexpr int NFREQ = 513;
constexpr int NW = 512;                       // frames per batch
constexpr int SIGLEN = HOP * (NW - 1);        // 130816
constexpr int TOTAL_LEN = NFFT + HOP*(NW-1);  // 131840
constexpr int NITER = 32;
constexpr int NSAMP = 131072;
constexpr int NMAG = BATCH * NW * NFREQ;      // 2101248
constexpr int NBLK = BATCH * NW / 4;          // 1024 persistent blocks
constexpr int NGRP = 32;                      // two-level barrier: 32 groups x 32 blocks

// LDS index padding (9/8 stride)
#define SL(i) ((i) + ((i) >> 3))
constexpr int WSL = 576;    // per-wave LDS slots: SL(511)=574, slot 575 = bin-512 home
constexpr int XSPAN = 4 * HOP + (NFFT - HOP); // 1792: union of 4 consecutive frame windows

#define WAVEFENCE() __builtin_amdgcn_wave_barrier()

// ---------------- Threefry-2x32-20, partitionable path (key = (0,1)) ----------------
__device__ __forceinline__ void tf_round(u32 &x0, u32 &x1, int r) {
  x0 += x1;
  x1 = (x1 << r) | (x1 >> (32 - r));
  x1 ^= x0;
}

__device__ __forceinline__ void threefry2(u32 c0, u32 c1, u32 &o0, u32 &o1) {
  const u32 k0 = 0u, k1 = 1u;
  const u32 k2 = 0x1BD11BDAu ^ k0 ^ k1;
  u32 x0 = c0 + k0, x1 = c1 + k1;
  tf_round(x0, x1, 13); tf_round(x0, x1, 15); tf_round(x0, x1, 26); tf_round(x0, x1, 6);
  x0 += k1; x1 += k2 + 1u;
  tf_round(x0, x1, 17); tf_round(x0, x1, 29); tf_round(x0, x1, 16); tf_round(x0, x1, 24);
  x0 += k2; x1 += k0 + 2u;
  tf_round(x0, x1, 13); tf_round(x0, x1, 15); tf_round(x0, x1, 26); tf_round(x0, x1, 6);
  x0 += k0; x1 += k1 + 3u;
  tf_round(x0, x1, 17); tf_round(x0, x1, 29); tf_round(x0, x1, 16); tf_round(x0, x1, 24);
  x0 += k1; x1 += k2 + 4u;
  tf_round(x0, x1, 13); tf_round(x0, x1, 15); tf_round(x0, x1, 26); tf_round(x0, x1, 6);
  x0 += k2; x1 += k0 + 5u;
  o0 = x0; o1 = x1;
}

// ---------------- init ----------------
__global__ __launch_bounds__(256) void k_init(float* __restrict__ win,
                                              float2* __restrict__ tw512f, double2* __restrict__ twh,
                                              float* __restrict__ wsq,
                                              float2* __restrict__ tprev,
                                              u32* __restrict__ bar)
{
  int idx = blockIdx.x * 256 + threadIdx.x;
  int stride = gridDim.x * 256;
  const double PI2 = 6.283185307179586476925286766559;
  for (int t = idx; t < NFFT; t += stride)
    win[t] = (float)(0.5 * (1.0 - cos(PI2 * (double)t / 1024.0)));  // _WIN f32
  for (int k = idx; k < 512; k += stride) {
    double th = -PI2 * (double)k / 512.0;
    tw512f[k] = make_float2((float)cos(th), (float)sin(th));  // e^{-2pi i k/512}
    double th2 = -PI2 * (double)k / 1024.0;
    double2 v2; v2.x = cos(th2); v2.y = sin(th2);
    twh[k] = v2;                                      // e^{-2pi i k/1024} (f64 boundary)
  }
  for (int j = idx; j < TOTAL_LEN; j += stride) {
    int gmax = j >> 8; if (gmax > NW - 1) gmax = NW - 1;
    int gmin = (j >= NFFT) ? ((j - (NFFT - 1) + 255) >> 8) : 0;
    float acc = 0.f;
    for (int g = gmin; g <= gmax; ++g) {
      float w = (float)(0.5 * (1.0 - cos(PI2 * (double)(j - (g << 8)) / 1024.0)));
      acc = __fadd_rn(acc, __fmul_rn(w, w));
    }
    wsq[j] = acc;
  }
  for (int i = idx; i < NMAG; i += stride)
    tprev[i] = make_float2(0.f, 0.f);
  for (int i = idx; i < NITER * (NGRP + 1); i += stride)
    bar[i] = 0u;                                      // grp[NITER][32] + root[NITER]
}

// ---------------- jax.image.resize bilinear ----------------
__device__ __forceinline__ void lin_taps(float sf, int in, int &i0, int &i1, float &w0, float &w1)
{
  if (sf <= 0.0f)                  { i0 = 0;      i1 = 0;      w0 = 1.0f; w1 = 0.0f; return; }
  if (sf >= (float)(in - 1))       { i0 = in - 1; i1 = in - 1; w0 = 1.0f; w1 = 0.0f; return; }
  i0 = (int)sf; i1 = i0 + 1;
  float x0 = __fsub_rn(sf, (float)i0);
  float a0 = __fsub_rn(1.0f, x0);
  float S  = __fadd_rn(a0, x0);
  w0 = __fdiv_rn(a0, S);
  w1 = __fdiv_rn(x0, S);
}

__device__ __forceinline__ float sf_H1(int H) {
  return __fadd_rn(__fmul_rn(__fadd_rn((float)H, 0.5f), 0.25f), -0.5f);
}
__device__ __forceinline__ float sf_W1(int W) {
  return __fadd_rn(__fmul_rn(__fadd_rn((float)W, 0.5f), 0.125f), -0.5f);
}
__device__ __forceinline__ float sf_H2(int K) {
  const float inv32 = (float)(1.0 / 4.0078125);
  return __fadd_rn(__fmul_rn(__fadd_rn((float)K, 0.5f), inv32), -0.5f);
}

__device__ __forceinline__ float fs_at(const float* __restrict__ pb, int H, int W)
{
  int r0, r1; float u0, u1;
  lin_taps(sf_H1(H), GH, r0, r1, u0, u1);
  int c0, c1; float v0, v1;
  lin_taps(sf_W1(W), GW, c0, c1, v0, v1);
  float t0 = __fmaf_rn(u1, pb[r1 * GW + c0], __fmul_rn(u0, pb[r0 * GW + c0]));
  float t1 = __fmaf_rn(u1, pb[r1 * GW + c1], __fmul_rn(u0, pb[r0 * GW + c1]));
  return __fmaf_rn(v1, t1, __fmul_rn(v0, t0));
}

__global__ __launch_bounds__(256) void k_fullspec(const float* __restrict__ p, float* __restrict__ fs)
{
  int idx = blockIdx.x * 256 + threadIdx.x;
  if (idx >= BATCH * FH * FW) return;
  int b = idx >> 16;
  int h = (idx >> 9) & (FH - 1);
  int w = idx & (FW - 1);
  fs[idx] = fs_at(p + b * (GH * GW), h, w);
}

__global__ __launch_bounds__(256) void k_mag(const float* __restrict__ p, float* __restrict__ mag)
{
  int idx = blockIdx.x * 256 + threadIdx.x;
  if (idx >= NMAG) return;
  int b = idx / (NW * NFREQ);
  int rem = idx - b * (NW * NFREQ);
  int f = rem / NFREQ;
  int k = rem - f * NFREQ;
  const float* pb = p + b * (GH * GW);
  int h0, h1; float wa, wb;
  lin_taps(sf_H2(k), FH, h0, h1, wa, wb);
  float fs0 = fs_at(pb, h0, f);
  float fs1 = fs_at(pb, h1, f);
  float P0 = __fmul_rn(__fmul_rn(fs0, fs0), 100.0f);
  float P1 = __fmul_rn(__fmul_rn(fs1, fs1), 100.0f);
  float lin = __fmaf_rn(wb, P1, __fmul_rn(wa, P0));
  mag[idx] = __fsqrt_rn(fmaxf(lin, 0.0f));
}

__global__ __launch_bounds__(256) void k_phase(float2* __restrict__ ang)
{
  int idx = blockIdx.x * 256 + threadIdx.x;
  if (idx >= NMAG) return;
  int b = idx / (NW * NFREQ);
  int rem = idx - b * (NW * NFREQ);
  int f = rem / NFREQ;
  int k = rem - f * NFREQ;
  u32 cnt = (u32)(b * (NFREQ * NW) + k * NW + f);
  u32 w0, w1;
  threefry2(0u, cnt, w0, w1);
  u32 bits = w0 ^ w1;
  float u = __uint_as_float((bits >> 9) | 0x3f800000u) - 1.0f;
  float th = __fmul_rn((float)6.283185307179586, u);
  double thd = (double)th;
  ang[idx] = make_float2((float)cos(thd), (float)sin(thd));
}

// ---------------- 512-pt FFT: radix-8^3 Stockham, ONE WAVE per transform ----------------
__device__ __forceinline__ float2 cadd2(float2 a, float2 b){ return make_float2(a.x+b.x, a.y+b.y); }
__device__ __forceinline__ float2 csub2(float2 a, float2 b){ return make_float2(a.x-b.x, a.y-b.y); }

template<bool INV>
__device__ __forceinline__ float2 twmul(float2 a, float2 w)
{
  float wy = INV ? -w.y : w.y;
  return make_float2(a.x*w.x - a.y*wy, a.x*wy + a.y*w.x);
}

template<bool INV>
__device__ __forceinline__ void bfly8(float2 x0, float2 x1, float2 x2, float2 x3,
                                      float2 x4, float2 x5, float2 x6, float2 x7,
                                      float2 &Y0, float2 &Y1, float2 &Y2, float2 &Y3,
                                      float2 &Y4, float2 &Y5, float2 &Y6, float2 &Y7)
{
  const float c = 0.70710678118654752440f;
  float2 u0 = cadd2(x0,x4), u1 = cadd2(x1,x5), u2 = cadd2(x2,x6), u3 = cadd2(x3,x7);
  float2 d0 = csub2(x0,x4), d1 = csub2(x1,x5), d2 = csub2(x2,x6), d3 = csub2(x3,x7);
  float2 w1, w2, w3;
  if (!INV) {
    w1 = make_float2(c*(d1.x + d1.y), c*(d1.y - d1.x));   // x w8^1 = (c,-c)
    w2 = make_float2(d2.y, -d2.x);                        // x (-i)
    w3 = make_float2(c*(d3.y - d3.x), -c*(d3.x + d3.y));  // x w8^3 = (-c,-c)
  } else {
    w1 = make_float2(c*(d1.x - d1.y), c*(d1.x + d1.y));   // x (c,c)
    w2 = make_float2(-d2.y, d2.x);                        // x (+i)
    w3 = make_float2(-c*(d3.x + d3.y), c*(d3.x - d3.y));  // x (-c,c)
  }
  float2 s0 = cadd2(u0,u2), s1 = cadd2(u1,u3), s2 = csub2(u0,u2);
  float2 e13 = csub2(u1,u3);
  float2 s3 = INV ? make_float2(-e13.y, e13.x) : make_float2(e13.y, -e13.x);
  float2 r0 = cadd2(d0,w2), r1 = cadd2(w1,w3), r2 = csub2(d0,w2);
  float2 e57 = csub2(w1,w3);
  float2 r3 = INV ? make_float2(-e57.y, e57.x) : make_float2(e57.y, -e57.x);
  Y0 = cadd2(s0,s1); Y4 = csub2(s0,s1);
  Y2 = cadd2(s2,s3); Y6 = csub2(s2,s3);
  Y1 = cadd2(r0,r1); Y5 = csub2(r0,r1);
  Y3 = cadd2(r2,r3); Y7 = csub2(r2,r3);
}

// stage 0: inputs in registers, twiddle base = t, write slots 8t+k
template<bool INV>
__device__ __forceinline__ void stage0_regs(float2* __restrict__ A, const float2* __restrict__ tw, int t,
    float2 x0, float2 x1, float2 x2, float2 x3, float2 x4, float2 x5, float2 x6, float2 x7)
{
  float2 Y0,Y1,Y2,Y3,Y4,Y5,Y6,Y7;
  bfly8<INV>(x0,x1,x2,x3,x4,x5,x6,x7, Y0,Y1,Y2,Y3,Y4,Y5,Y6,Y7);
  int ob = 8 * t;
  A[SL(ob + 0)] = Y0;
  A[SL(ob + 1)] = twmul<INV>(Y1, tw[t]);
  A[SL(ob + 2)] = twmul<INV>(Y2, tw[2 * t]);
  A[SL(ob + 3)] = twmul<INV>(Y3, tw[3 * t]);
  A[SL(ob + 4)] = twmul<INV>(Y4, tw[4 * t]);
  A[SL(ob + 5)] = twmul<INV>(Y5, tw[5 * t]);
  A[SL(ob + 6)] = twmul<INV>(Y6, tw[6 * t]);
  A[SL(ob + 7)] = twmul<INV>(Y7, tw[7 * t]);
}

// stage 1 (L=8): in-place LDS->LDS, twiddle base = 8p, write slots q+64p+8k
template<bool INV>
__device__ __forceinline__ void stage_mid(float2* __restrict__ A, const float2* __restrict__ tw, int t)
{
  float2 x0 = A[SL(t)],       x1 = A[SL(t + 64)],  x2 = A[SL(t + 128)], x3 = A[SL(t + 192)];
  float2 x4 = A[SL(t + 256)], x5 = A[SL(t + 320)], x6 = A[SL(t + 384)], x7 = A[SL(t + 448)];
  float2 Y0,Y1,Y2,Y3,Y4,Y5,Y6,Y7;
  bfly8<INV>(x0,x1,x2,x3,x4,x5,x6,x7, Y0,Y1,Y2,Y3,Y4,Y5,Y6,Y7);
  WAVEFENCE();
  int p = t >> 3, q = t & 7;
  int base = 8 * p;
  int ob = q + 64 * p;
  A[SL(ob)]      = Y0;
  A[SL(ob + 8)]  = twmul<INV>(Y1, tw[base]);
  A[SL(ob + 16)] = twmul<INV>(Y2, tw[2 * base]);
  A[SL(ob + 24)] = twmul<INV>(Y3, tw[3 * base]);
  A[SL(ob + 32)] = twmul<INV>(Y4, tw[4 * base]);
  A[SL(ob + 40)] = twmul<INV>(Y5, tw[5 * base]);
  A[SL(ob + 48)] = twmul<INV>(Y6, tw[6 * base]);
  A[SL(ob + 56)] = twmul<INV>(Y7, tw[7 * base]);
}

// stage 2 (L=64, base=0): lane-local in-place, result natural order A[t+64k]
template<bool INV>
__device__ __forceinline__ void stage_last_lds(float2* __restrict__ A, int t)
{
  float2 x0 = A[SL(t)],       x1 = A[SL(t + 64)],  x2 = A[SL(t + 128)], x3 = A[SL(t + 192)];
  float2 x4 = A[SL(t + 256)], x5 = A[SL(t + 320)], x6 = A[SL(t + 384)], x7 = A[SL(t + 448)];
  float2 Y0,Y1,Y2,Y3,Y4,Y5,Y6,Y7;
  bfly8<INV>(x0,x1,x2,x3,x4,x5,x6,x7, Y0,Y1,Y2,Y3,Y4,Y5,Y6,Y7);
  WAVEFENCE();
  A[SL(t)]       = Y0; A[SL(t + 64)]  = Y1; A[SL(t + 128)] = Y2; A[SL(t + 192)] = Y3;
  A[SL(t + 256)] = Y4; A[SL(t + 320)] = Y5; A[SL(t + 384)] = Y6; A[SL(t + 448)] = Y7;
}

// stage 2 -> registers (inverse tail): Yk = time point t+64k
template<bool INV>
__device__ __forceinline__ void stage_last_regs(const float2* __restrict__ A, int t,
    float2 &Y0, float2 &Y1, float2 &Y2, float2 &Y3, float2 &Y4, float2 &Y5, float2 &Y6, float2 &Y7)
{
  float2 x0 = A[SL(t)],       x1 = A[SL(t + 64)],  x2 = A[SL(t + 128)], x3 = A[SL(t + 192)];
  float2 x4 = A[SL(t + 256)], x5 = A[SL(t + 320)], x6 = A[SL(t + 384)], x7 = A[SL(t + 448)];
  bfly8<INV>(x0,x1,x2,x3,x4,x5,x6,x7, Y0,Y1,Y2,Y3,Y4,Y5,Y6,Y7);
}

// momentum phase update, tprev in GLOBAL (fallback path); writes angle to LDS slot
__device__ __forceinline__ void upd_bin(float2* __restrict__ prow, float2* __restrict__ A,
                                        int k, double rx, double ry, float cf)
{
  float rxf = (float)rx, ryf = (float)ry;
  float2 pv = prow[k];
  float ax = __fsub_rn(rxf, __fmul_rn(pv.x, cf));
  float ay = __fsub_rn(ryf, __fmul_rn(pv.y, cf));
  double dx = (double)ax, dy = (double)ay;
  float d = (float)sqrt(dx * dx + dy * dy);
  float d2 = __fadd_rn(d, 1e-16f);
  float inv = __fdiv_rn(1.0f, d2);
  int slot = (k == 512) ? (WSL - 1) : SL(k);
  A[slot] = make_float2(__fmul_rn(ax, inv), __fmul_rn(ay, inv));
  prow[k] = make_float2(rxf, ryf);
}

// momentum phase update, tprev in a REGISTER (persistent path)
__device__ __forceinline__ void upd_reg(float2 &tprev, float2* __restrict__ A,
                                        int slot, double rx, double ry, float cf)
{
  float rxf = (float)rx, ryf = (float)ry;
  float ax = __fsub_rn(rxf, __fmul_rn(tprev.x, cf));
  float ay = __fsub_rn(ryf, __fmul_rn(tprev.y, cf));
  double dx = (double)ax, dy = (double)ay;
  float d = (float)sqrt(dx * dx + dy * dy);
  float d2 = __fadd_rn(d, 1e-16f);
  float inv = __fdiv_rn(1.0f, d2);
  A[slot] = make_float2(__fmul_rn(ax, inv), __fmul_rn(ay, inv));
  tprev = make_float2(rxf, ryf);
}

// ---------------- initial ISTFT: wave-per-frame ----------------
__global__ __launch_bounds__(256) void k_istft(const float* __restrict__ mag, const float2* __restrict__ ang,
                                               float* __restrict__ frames,
                                               const float2* __restrict__ tw512f,
                                               const double2* __restrict__ twh,
                                               const float* __restrict__ win)
{
  __shared__ float2 ldsA[4 * WSL];
  __shared__ float2 twl[512];
  int tid = threadIdx.x;
  for (int i = tid; i < 512; i += 256) twl[i] = tw512f[i];
  __syncthreads();

  int wv = tid >> 6;
  int t  = tid & 63;
  int bf = (blockIdx.x << 2) + wv;
  float2* A = ldsA + wv * WSL;
  const float*  mrow = mag + bf * NFREQ;
  const float2* arow = ang + bf * NFREQ;

  // Hermitian pack straight into registers (points k = t + 64j)
  float2 z0, z1, z2, z3, z4, z5, z6, z7;
#define PACKG(j, zj) { \
    int k = t + 64 * j; \
    if (k == 0) { \
      float m1 = mrow[0];   float2 a1 = arow[0]; \
      float m2 = mrow[512]; float2 a2 = arow[512]; \
      float S1x = __fmul_rn(m1, a1.x); \
      float S2x = __fmul_rn(m2, a2.x); \
      zj = make_float2((float)(0.5 * ((double)S1x + (double)S2x)), \
                       (float)(0.5 * ((double)S1x - (double)S2x))); \
    } else { \
      int k2 = 512 - k; \
      float m1 = mrow[k];  float2 a1 = arow[k]; \
      float m2 = mrow[k2]; float2 a2 = arow[k2]; \
      float S1x = __fmul_rn(m1, a1.x), S1y = __fmul_rn(m1, a1.y); \
      float S2x = __fmul_rn(m2, a2.x), S2y = __fmul_rn(m2, a2.y); \
      double Xex = 0.5 * ((double)S1x + (double)S2x); \
      double Xey = 0.5 * ((double)S1y - (double)S2y); \
      double Dx  = 0.5 * ((double)S1x - (double)S2x); \
      double Dy  = 0.5 * ((double)S1y + (double)S2y); \
      double2 w = twh[k]; \
      double ux = w.x * Dx + w.y * Dy; \
      double uy = w.x * Dy - w.y * Dx; \
      zj = make_float2((float)(Xex - uy), (float)(Xey + ux)); \
    } }
  PACKG(0, z0) PACKG(1, z1) PACKG(2, z2) PACKG(3, z3)
  PACKG(4, z4) PACKG(5, z5) PACKG(6, z6) PACKG(7, z7)

  stage0_regs<true>(A, twl, t, z0, z1, z2, z3, z4, z5, z6, z7);
  WAVEFENCE();
  stage_mid<true>(A, twl, t);
  WAVEFENCE();
  float2 y0, y1, y2, y3, y4, y5, y6, y7;
  stage_last_regs<true>(A, t, y0, y1, y2, y3, y4, y5, y6, y7);

  const float sc = 1.0f / 512.0f;
  const float2* win2 = (const float2*)win;
  float2* frow2 = (float2*)(frames + bf * NFFT);
#define STOREF(k, yk) { int m = t + 64 * k; float2 wv2 = win2[m]; \
    frow2[m] = make_float2(__fmul_rn(__fmul_rn(yk.x, sc), wv2.x), \
                           __fmul_rn(__fmul_rn(yk.y, sc), wv2.y)); }
  STOREF(0, y0) STOREF(1, y1) STOREF(2, y2) STOREF(3, y3)
  STOREF(4, y4) STOREF(5, y5) STOREF(6, y6) STOREF(7, y7)
}

// f32 OLA sample at wsq-coordinate j
__device__ __forceinline__ float sig_sample(const float* __restrict__ fb, const float* __restrict__ wsq, int j)
{
  int gmax = j >> 8; if (gmax > NW - 1) gmax = NW - 1;
  int gmin = (j >= NFFT) ? ((j - (NFFT - 1) + 255) >> 8) : 0;
  float acc = 0.f;
  for (int g = gmin; g <= gmax; ++g)
    acc = __fadd_rn(acc, fb[g * NFFT + (j - (g << 8))]);
  float wv = wsq[j];
  return __fdiv_rn(acc, wv > 1e-11f ? wv : 1.0f);
}

// ================= FALLBACK: per-iteration fused kernel (R6, verified) =================
__global__ __launch_bounds__(256) void k_fused(const float* __restrict__ frames_in,
                                               const float* __restrict__ wsq,
                                               const float* __restrict__ win,
                                               const float2* __restrict__ tw512f,
                                               const double2* __restrict__ twh,
                                               const float* __restrict__ mag,
                                               float2* __restrict__ tprev,
                                               float* __restrict__ frames_out)
{
  __shared__ float2 ldsA[4 * WSL];
  __shared__ float2 twl[512];
  __shared__ float2 xpL2[XSPAN / 2];
  float* xpL = (float*)xpL2;
  int tid = threadIdx.x;
  for (int i = tid; i < 512; i += 256) twl[i] = tw512f[i];

  int bf0 = blockIdx.x << 2;
  int b  = bf0 >> 9;
  int f0 = bf0 & (NW - 1);
  const float* fb = frames_in + b * (NW * NFFT);
  int xbase = f0 * HOP;
#pragma unroll
  for (int c = 0; c < XSPAN / 256; ++c) {
    int s = tid + 256 * c;
    int j = xbase + s;
    int n = j - 512;
    if (n < 0) n = -n;
    if (n >= SIGLEN) n = 2 * SIGLEN - 2 - n;
    xpL[s] = sig_sample(fb, wsq, n + 512);
  }
  __syncthreads();

  int wv = tid >> 6;
  int t  = tid & 63;
  int bf = bf0 + wv;
  float2* A = ldsA + wv * WSL;
  const float2* win2 = (const float2*)win;

  const float2* xrow2 = (const float2*)(xpL + wv * HOP);
  float2 x0, x1, x2, x3, x4, x5, x6, x7;
#define LOADXF(j, xj) { float2 xv = xrow2[t + 64 * j]; float2 wv2 = win2[t + 64 * j]; \
    xj = make_float2(__fmul_rn(xv.x, wv2.x), __fmul_rn(xv.y, wv2.y)); }
  LOADXF(0, x0) LOADXF(1, x1) LOADXF(2, x2) LOADXF(3, x3)
  LOADXF(4, x4) LOADXF(5, x5) LOADXF(6, x6) LOADXF(7, x7)
  stage0_regs<false>(A, twl, t, x0, x1, x2, x3, x4, x5, x6, x7);
  WAVEFENCE();
  stage_mid<false>(A, twl, t);
  WAVEFENCE();
  stage_last_lds<false>(A, t);
  WAVEFENCE();

  float2* prow = tprev + bf * NFREQ;
  const float cf = (float)(0.99 / 1.99);
#pragma unroll
  for (int j = 0; j < 4; ++j) {
    int k = t + 64 * j;
    if (k == 0) {
      float2 Z0 = A[SL(0)];
      double rx0 = (double)Z0.x + (double)Z0.y;
      double rx5 = (double)Z0.x - (double)Z0.y;
      upd_bin(prow, A, 0,   rx0, 0.0, cf);
      upd_bin(prow, A, 512, rx5, 0.0, cf);
    } else {
      int kc = 512 - k;
      float2 Zk = A[SL(k)];
      float2 Zc = A[SL(kc)];
      double Xex = 0.5 * ((double)Zk.x + (double)Zc.x);
      double Xey = 0.5 * ((double)Zk.y - (double)Zc.y);
      double Gx  = 0.5 * ((double)Zk.x - (double)Zc.x);
      double Gy  = 0.5 * ((double)Zk.y + (double)Zc.y);
      double2 w = twh[k];
      double P = w.x * Gy + w.y * Gx;
      double Q = w.y * Gy - w.x * Gx;
      upd_bin(prow, A, k,  Xex + P, Xey + Q, cf);
      upd_bin(prow, A, kc, Xex - P, Q - Xey, cf);
    }
  }
  if (t == 0) {
    float2 Zk = A[SL(256)];
    double Xex = 0.5 * ((double)Zk.x + (double)Zk.x);
    double Gy  = 0.5 * ((double)Zk.y + (double)Zk.y);
    double2 w = twh[256];
    double P = w.x * Gy;
    double Q = w.y * Gy;
    upd_bin(prow, A, 256, Xex + P, Q, cf);
  }
  WAVEFENCE();

  const float* mrow = mag + bf * NFREQ;
  float2 z0, z1, z2, z3, z4, z5, z6, z7;
#define PACKLF(j, zj) { \
    int k = t + 64 * j; \
    if (k == 0) { \
      float m1 = mrow[0];   float2 a1 = A[SL(0)]; \
      float m2 = mrow[512]; float2 a2 = A[WSL - 1]; \
      float S1x = __fmul_rn(m1, a1.x); \
      float S2x = __fmul_rn(m2, a2.x); \
      zj = make_float2((float)(0.5 * ((double)S1x + (double)S2x)), \
                       (float)(0.5 * ((double)S1x - (double)S2x))); \
    } else { \
      int k2 = 512 - k; \
      float m1 = mrow[k];  float2 a1 = A[SL(k)]; \
      float m2 = mrow[k2]; float2 a2 = A[SL(k2)]; \
      float S1x = __fmul_rn(m1, a1.x), S1y = __fmul_rn(m1, a1.y); \
      float S2x = __fmul_rn(m2, a2.x), S2y = __fmul_rn(m2, a2.y); \
      double Xex = 0.5 * ((double)S1x + (double)S2x); \
      double Xey = 0.5 * ((double)S1y - (double)S2y); \
      double Dx  = 0.5 * ((double)S1x - (double)S2x); \
      double Dy  = 0.5 * ((double)S1y + (double)S2y); \
      double2 w = twh[k]; \
      double ux = w.x * Dx + w.y * Dy; \
      double uy = w.x * Dy - w.y * Dx; \
      zj = make_float2((float)(Xex - uy), (float)(Xey + ux)); \
    } }
  PACKLF(0, z0) PACKLF(1, z1) PACKLF(2, z2) PACKLF(3, z3)
  PACKLF(4, z4) PACKLF(5, z5) PACKLF(6, z6) PACKLF(7, z7)
  WAVEFENCE();

  stage0_regs<true>(A, twl, t, z0, z1, z2, z3, z4, z5, z6, z7);
  WAVEFENCE();
  stage_mid<true>(A, twl, t);
  WAVEFENCE();
  float2 y0, y1, y2, y3, y4, y5, y6, y7;
  stage_last_regs<true>(A, t, y0, y1, y2, y3, y4, y5, y6, y7);

  const float sc = 1.0f / 512.0f;
  float2* frow2 = (float2*)(frames_out + bf * NFFT);
  STOREF(0, y0) STOREF(1, y1) STOREF(2, y2) STOREF(3, y3)
  STOREF(4, y4) STOREF(5, y5) STOREF(6, y6) STOREF(7, y7)
}

// ================= PERSISTENT cooperative loop with own 2-level grid barrier =================
// All fences explicit (agent scope) -> cross-XCD safe. tprev in registers (-33.6 MB/iter),
// mag row in 16 registers (-8.4 MB/iter). LDS 29.7 KB -> 5 blocks/CU headroom (need 4).
__device__ __forceinline__ void grid_barrier(u32* __restrict__ grp, u32* __restrict__ root, int it)
{
  __syncthreads();
  if (threadIdx.x == 0) {
    __threadfence();                                   // release this block's frames stores
    int g = (int)(blockIdx.x >> 5);                    // 32 groups of 32 blocks
    if (atomicAdd(&grp[it * NGRP + g], 1u) == 31u) {
      __threadfence();                                 // release the group's accumulated deps
      atomicAdd(&root[it], 1u);
    }
    while (__hip_atomic_load(&root[it], __ATOMIC_RELAXED, __HIP_MEMORY_SCOPE_AGENT) < (u32)NGRP)
      __builtin_amdgcn_s_sleep(2);
    __threadfence();                                   // acquire all blocks' stores
  }
  __syncthreads();
}

__global__ __launch_bounds__(256, 4) void k_loop(float* __restrict__ framesA,
                                                 float* __restrict__ framesB,
                                                 const float* __restrict__ wsq,
                                                 const float* __restrict__ win,
                                                 const float2* __restrict__ tw512f,
                                                 const double2* __restrict__ twh,
                                                 const float* __restrict__ mag,
                                                 u32* __restrict__ grp,
                                                 u32* __restrict__ root)
{
  __shared__ float2 ldsA[4 * WSL];            // 18432 B
  __shared__ float2 twl[512];                 //  4096 B
  __shared__ float2 xpL2[XSPAN / 2];          //  7168 B   (total 29696 B)
  float* xpL = (float*)xpL2;

  int tid = threadIdx.x;
  int wv = tid >> 6;
  int t  = tid & 63;
  int bf0 = blockIdx.x << 2;
  int b  = bf0 >> 9;
  int f0 = bf0 & (NW - 1);
  int bf = bf0 + wv;
  float2* A = ldsA + wv * WSL;
  const float2* win2 = (const float2*)win;

  for (int i = tid; i < 512; i += 256) twl[i] = tw512f[i];

  // mag row -> 16 registers (constant across iterations); mg_j = mrow[t+64j], mh_j = mrow[512-t-64j]
  const float* mrow = mag + bf * NFREQ;
  float mg0 = mrow[t],       mg1 = mrow[t + 64],  mg2 = mrow[t + 128], mg3 = mrow[t + 192];
  float mg4 = mrow[t + 256], mg5 = mrow[t + 320], mg6 = mrow[t + 384], mg7 = mrow[t + 448];
  float mh0 = mrow[512 - t], mh1 = mrow[448 - t], mh2 = mrow[384 - t], mh3 = mrow[320 - t];
  float mh4 = mrow[256 - t], mh5 = mrow[192 - t], mh6 = mrow[128 - t], mh7 = mrow[64 - t];

  // persistent tprev registers: lane t owns bins k=t+64j (tp_j) and 512-k (tq_j); lane 0 also bin 256 (tr)
  float2 tp0 = make_float2(0.f, 0.f), tp1 = tp0, tp2 = tp0, tp3 = tp0;
  float2 tq0 = tp0, tq1 = tp0, tq2 = tp0, tq3 = tp0;
  float2 tr  = tp0;

  const float cf = (float)(0.99 / 1.99);
  const float sc = 1.0f / 512.0f;
  int xbase = f0 * HOP;

  for (int it = 0; it < NITER; ++it) {
    const float* fin  = (it & 1) ? framesB : framesA;
    float*       fout = (it & 1) ? framesA : framesB;
    const float* fb = fin + b * (NW * NFFT);

    // ---- block-shared OLA staging (bit-identical ops to k_sig) ----
#pragma unroll
    for (int c = 0; c < XSPAN / 256; ++c) {
      int s = tid + 256 * c;
      int j = xbase + s;
      int n = j - 512;
      if (n < 0) n = -n;
      if (n >= SIGLEN) n = 2 * SIGLEN - 2 - n;
      xpL[s] = sig_sample(fb, wsq, n + 512);
    }
    __syncthreads();

    // ---- forward ----
    const float2* xrow2 = (const float2*)(xpL + wv * HOP);
    float2 x0, x1, x2, x3, x4, x5, x6, x7;
#define LOADX2(j, xj) { float2 xv = xrow2[t + 64 * j]; float2 wv2 = win2[t + 64 * j]; \
    xj = make_float2(__fmul_rn(xv.x, wv2.x), __fmul_rn(xv.y, wv2.y)); }
    LOADX2(0, x0) LOADX2(1, x1) LOADX2(2, x2) LOADX2(3, x3)
    LOADX2(4, x4) LOADX2(5, x5) LOADX2(6, x6) LOADX2(7, x7)
    stage0_regs<false>(A, twl, t, x0, x1, x2, x3, x4, x5, x6, x7);
    WAVEFENCE();
    stage_mid<false>(A, twl, t);
    WAVEFENCE();
    stage_last_lds<false>(A, t);
    WAVEFENCE();

    // ---- unpack + momentum update into register tprev ----
#define UPDP2(j, tpj, tqj) { \
      int k = t + 64 * (j); \
      if ((j) == 0 && k == 0) { \
        float2 Z0 = A[SL(0)]; \
        double rx0 = (double)Z0.x + (double)Z0.y; \
        double rx5 = (double)Z0.x - (double)Z0.y; \
        upd_reg(tpj, A, SL(0),   rx0, 0.0, cf); \
        upd_reg(tqj, A, WSL - 1, rx5, 0.0, cf); \
      } else { \
        int kc = 512 - k; \
        float2 Zk = A[SL(k)]; \
        float2 Zc = A[SL(kc)]; \
        double Xex = 0.5 * ((double)Zk.x + (double)Zc.x); \
        double Xey = 0.5 * ((double)Zk.y - (double)Zc.y); \
        double Gx  = 0.5 * ((double)Zk.x - (double)Zc.x); \
        double Gy  = 0.5 * ((double)Zk.y + (double)Zc.y); \
        double2 w = twh[k]; \
        double P = w.x * Gy + w.y * Gx; \
        double Q = w.y * Gy - w.x * Gx; \
        upd_reg(tpj, A, SL(k),  Xex + P, Xey + Q, cf); \
        upd_reg(tqj, A, SL(kc), Xex - P, Q - Xey, cf); \
      } }
    UPDP2(0, tp0, tq0)
    UPDP2(1, tp1, tq1)
    UPDP2(2, tp2, tq2)
    UPDP2(3, tp3, tq3)
    if (t == 0) {
      float2 Zk = A[SL(256)];
      double Xex = 0.5 * ((double)Zk.x + (double)Zk.x);
      double Gy  = 0.5 * ((double)Zk.y + (double)Zk.y);
      double2 w = twh[256];
      double P = w.x * Gy;
      double Q = w.y * Gy;
      upd_reg(tr, A, SL(256), Xex + P, Q, cf);
    }
    WAVEFENCE();

    // ---- inverse: Hermitian pack (register mag x LDS angles) ----
    float2 z0, z1, z2, z3, z4, z5, z6, z7;
#define PACKL2(j, zj, mgj, mhj) { \
      int k = t + 64 * j; \
      if (k == 0) { \
        float2 a1 = A[SL(0)]; \
        float2 a2 = A[WSL - 1]; \
        float S1x = __fmul_rn(mgj, a1.x); \
        float S2x = __fmul_rn(mhj, a2.x); \
        zj = make_float2((float)(0.5 * ((double)S1x + (double)S2x)), \
                         (float)(0.5 * ((double)S1x - (double)S2x))); \
      } else { \
        int k2 = 512 - k; \
        float2 a1 = A[SL(k)]; \
        float2 a2 = A[SL(k2)]; \
        float S1x = __fmul_rn(mgj, a1.x), S1y = __fmul_rn(mgj, a1.y); \
        float S2x = __fmul_rn(mhj, a2.x), S2y = __fmul_rn(mhj, a2.y); \
        double Xex = 0.5 * ((double)S1x + (double)S2x); \
        double Xey = 0.5 * ((double)S1y - (double)S2y); \
        double Dx  = 0.5 * ((double)S1x - (double)S2x); \
        double Dy  = 0.5 * ((double)S1y + (double)S2y); \
        double2 w = twh[k]; \
        double ux = w.x * Dx + w.y * Dy; \
        double uy = w.x * Dy - w.y * Dx; \
        zj = make_float2((float)(Xex - uy), (float)(Xey + ux)); \
      } }
    PACKL2(0, z0, mg0, mh0) PACKL2(1, z1, mg1, mh1) PACKL2(2, z2, mg2, mh2) PACKL2(3, z3, mg3, mh3)
    PACKL2(4, z4, mg4, mh4) PACKL2(5, z5, mg5, mh5) PACKL2(6, z6, mg6, mh6) PACKL2(7, z7, mg7, mh7)
    WAVEFENCE();

    stage0_regs<true>(A, twl, t, z0, z1, z2, z3, z4, z5, z6, z7);
    WAVEFENCE();
    stage_mid<true>(A, twl, t);
    WAVEFENCE();
    float2 y0, y1, y2, y3, y4, y5, y6, y7;
    stage_last_regs<true>(A, t, y0, y1, y2, y3, y4, y5, y6, y7);

    float2* frow2 = (float2*)(fout + bf * NFFT);
    STOREF(0, y0) STOREF(1, y1) STOREF(2, y2) STOREF(3, y3)
    STOREF(4, y4) STOREF(5, y5) STOREF(6, y6) STOREF(7, y7)

    if (it != NITER - 1)
      grid_barrier(grp, root, it);   // release frames stores; acquire all blocks' stores
  }
}

// ---------------- final OLA -> audio f32 + per-block |max| ----------------
__global__ __launch_bounds__(256) void k_ola(const float* __restrict__ frames, const float* __restrict__ wsq,
                                             float* __restrict__ audio, float* __restrict__ partial)
{
  int idx = blockIdx.x * 256 + threadIdx.x;
  int b  = idx >> 17;
  int nn = idx & (NSAMP - 1);
  float v = 0.f;
  if (nn < SIGLEN)
    v = sig_sample(frames + b * (NW * NFFT), wsq, nn + 512);
  audio[idx] = v;
  __shared__ float red[256];
  red[threadIdx.x] = fabsf(v);
  __syncthreads();
  for (int s = 128; s > 0; s >>= 1) {
    if (threadIdx.x < s) red[threadIdx.x] = fmaxf(red[threadIdx.x], red[threadIdx.x + s]);
    __syncthreads();
  }
  if (threadIdx.x == 0) partial[blockIdx.x] = red[0];
}

constexpr int OLA_BLK_PER_B = NSAMP / 256;   // 512

__global__ __launch_bounds__(256) void k_max2(const float* __restrict__ partial, float* __restrict__ maxbuf)
{
  int b = blockIdx.x;
  float m = 0.f;
  for (int i = threadIdx.x; i < OLA_BLK_PER_B; i += 256)
    m = fmaxf(m, partial[b * OLA_BLK_PER_B + i]);
  __shared__ float red[256];
  red[threadIdx.x] = m;
  __syncthreads();
  for (int s = 128; s > 0; s >>= 1) {
    if (threadIdx.x < s) red[threadIdx.x] = fmaxf(red[threadIdx.x], red[threadIdx.x + s]);
    __syncthreads();
  }
  if (threadIdx.x == 0) maxbuf[b] = red[0];
}

__global__ __launch_bounds__(256) void k_norm(const float* __restrict__ audio, const float* __restrict__ maxbuf,
                                              float* __restrict__ out)
{
  int idx = blockIdx.x * 256 + threadIdx.x;
  int b = idx >> 17;
  float m = fmaxf(maxbuf[b], 1e-8f);
  out[idx] = __fmul_rn(__fdiv_rn(audio[idx], m), 0.9f);
}

extern "C" void kernel_launch(void* const* d_in, const int* in_sizes, int n_in,
                              void* d_out, int out_size, void* d_ws, size_t ws_size,
                              hipStream_t stream)
{
  const float* params = (const float*)d_in[0];
  float* out   = (float*)d_out;
  float* audio_out = out;                   // BATCH*NSAMP
  float* fs        = out + BATCH * NSAMP;   // BATCH*FH*FW (full_spec output)

  float2*  tw512f = (float2*)d_ws;                         // 512
  double2* twh    = (double2*)(tw512f + 512);              // 512
  float2*  ang    = (float2*)(twh + 512);                  // NMAG c64 (initial phases; dead after k_istft)
  float2*  tprev  = ang + NMAG;                            // NMAG c64 (fallback path only)
  float*   framesA= (float*)(tprev + NMAG);                // BATCH*NW*NFFT f32
  float*   mag    = framesA + BATCH * NW * NFFT;           // NMAG f32
  float*   win    = mag + NMAG;                            // NFFT
  float*   wsq    = win + NFFT;                            // TOTAL_LEN
  float*   audio32= wsq + TOTAL_LEN;                       // BATCH*NSAMP
  float*   maxbuf = audio32 + BATCH * NSAMP;               // BATCH
  float*   partial= maxbuf + BATCH;                        // BATCH*OLA_BLK_PER_B
  u32*     bar    = (u32*)(partial + BATCH * OLA_BLK_PER_B); // NITER*(NGRP+1) u32
  u32*     grpbar = bar;                                   // [NITER][NGRP]
  u32*     rootbar= bar + NITER * NGRP;                    // [NITER]
  // frames ping-pong buffer B aliases the dead ang region:
  // NMAG*8 = 16,809,984 B >= BATCH*NW*NFFT*4 = 16,777,216 B; 16B-aligned.
  float*   framesB= (float*)ang;

  k_init<<<512, 256, 0, stream>>>(win, tw512f, twh, wsq, tprev, bar);
  k_fullspec<<<(BATCH * FH * FW) / 256, 256, 0, stream>>>(params, fs);
  k_mag<<<(NMAG + 255) / 256, 256, 0, stream>>>(params, mag);
  k_phase<<<(NMAG + 255) / 256, 256, 0, stream>>>(ang);

  k_istft<<<NBLK, 256, 0, stream>>>(mag, (const float2*)ang, framesA, tw512f, twh, win);

  // persistent cooperative loop; on ANY launch error fall back to the verified
  // per-iteration path (bit-identical math, ~R6 speed).
  void* args[] = { (void*)&framesA, (void*)&framesB, (void*)&wsq, (void*)&win,
                   (void*)&tw512f, (void*)&twh, (void*)&mag,
                   (void*)&grpbar, (void*)&rootbar };
  hipError_t ce = hipLaunchCooperativeKernel((const void*)k_loop, dim3(NBLK), dim3(256),
                                             args, 0, stream);
  if (ce != hipSuccess) {
    float* fin  = framesA;
    float* fout = framesB;
    for (int it = 0; it < NITER; ++it) {
      k_fused<<<NBLK, 256, 0, stream>>>(fin, wsq, win, tw512f, twh, mag, tprev, fout);
      float* tmp = fin; fin = fout; fout = tmp;
    }
  }
  // NITER even -> final frames in framesA on both paths
  k_ola<<<(BATCH * NSAMP) / 256, 256, 0, stream>>>(framesA, wsq, audio32, partial);
  k_max2<<<BATCH, 256, 0, stream>>>(partial, maxbuf);
  k_norm<<<(BATCH * NSAMP) / 256, 256, 0, stream>>>(audio32, maxbuf, audio_out);
}

// Round 9
// 1426.091 us; speedup vs baseline: 2.2145x; 2.2145x over previous
//
#include <hip/hip_runtime.h>

typedef unsigned int u32;

constexpr int BATCH = 8;
constexpr int GH = 32, GW = 64;
constexpr int FH = 128, FW = 512;
constexpr int NFFT = 1024;
constexpr int HOP = 256;
constexpr int NFREQ = 513;
constexpr int NW = 512;                       // frames per batch
constexpr int SIGLEN = HOP * (NW - 1);        // 130816
constexpr int TOTAL_LEN = NFFT + HOP*(NW-1);  // 131840
constexpr int NITER = 32;
constexpr int NSAMP = 131072;
constexpr int NMAG = BATCH * NW * NFREQ;      // 2101248
constexpr int NBLK = BATCH * NW / 4;          // 1024 persistent blocks
constexpr int FPAD = 16;                      // flag padding: 1 u32 per 64B line

// LDS index padding (9/8 stride)
#define SL(i) ((i) + ((i) >> 3))
constexpr int WSL = 576;    // per-wave LDS slots: SL(511)=574, slot 575 = bin-512 home
constexpr int XSPAN = 4 * HOP + (NFFT - HOP); // 1792: union of 4 consecutive frame windows

#define WAVEFENCE() __builtin_amdgcn_wave_barrier()

// ---------------- Threefry-2x32-20, partitionable path (key = (0,1)) ----------------
__device__ __forceinline__ void tf_round(u32 &x0, u32 &x1, int r) {
  x0 += x1;
  x1 = (x1 << r) | (x1 >> (32 - r));
  x1 ^= x0;
}

__device__ __forceinline__ void threefry2(u32 c0, u32 c1, u32 &o0, u32 &o1) {
  const u32 k0 = 0u, k1 = 1u;
  const u32 k2 = 0x1BD11BDAu ^ k0 ^ k1;
  u32 x0 = c0 + k0, x1 = c1 + k1;
  tf_round(x0, x1, 13); tf_round(x0, x1, 15); tf_round(x0, x1, 26); tf_round(x0, x1, 6);
  x0 += k1; x1 += k2 + 1u;
  tf_round(x0, x1, 17); tf_round(x0, x1, 29); tf_round(x0, x1, 16); tf_round(x0, x1, 24);
  x0 += k2; x1 += k0 + 2u;
  tf_round(x0, x1, 13); tf_round(x0, x1, 15); tf_round(x0, x1, 26); tf_round(x0, x1, 6);
  x0 += k0; x1 += k1 + 3u;
  tf_round(x0, x1, 17); tf_round(x0, x1, 29); tf_round(x0, x1, 16); tf_round(x0, x1, 24);
  x0 += k1; x1 += k2 + 4u;
  tf_round(x0, x1, 13); tf_round(x0, x1, 15); tf_round(x0, x1, 26); tf_round(x0, x1, 6);
  x0 += k2; x1 += k0 + 5u;
  o0 = x0; o1 = x1;
}

// ---------------- init ----------------
__global__ __launch_bounds__(256) void k_init(float* __restrict__ win,
                                              float2* __restrict__ tw512f, double2* __restrict__ twh,
                                              float* __restrict__ wsq,
                                              float2* __restrict__ tprev,
                                              u32* __restrict__ flags)
{
  int idx = blockIdx.x * 256 + threadIdx.x;
  int stride = gridDim.x * 256;
  const double PI2 = 6.283185307179586476925286766559;
  for (int t = idx; t < NFFT; t += stride)
    win[t] = (float)(0.5 * (1.0 - cos(PI2 * (double)t / 1024.0)));  // _WIN f32
  for (int k = idx; k < 512; k += stride) {
    double th = -PI2 * (double)k / 512.0;
    tw512f[k] = make_float2((float)cos(th), (float)sin(th));  // e^{-2pi i k/512}
    double th2 = -PI2 * (double)k / 1024.0;
    double2 v2; v2.x = cos(th2); v2.y = sin(th2);
    twh[k] = v2;                                      // e^{-2pi i k/1024} (f64 boundary)
  }
  for (int j = idx; j < TOTAL_LEN; j += stride) {
    int gmax = j >> 8; if (gmax > NW - 1) gmax = NW - 1;
    int gmin = (j >= NFFT) ? ((j - (NFFT - 1) + 255) >> 8) : 0;
    float acc = 0.f;
    for (int g = gmin; g <= gmax; ++g) {
      float w = (float)(0.5 * (1.0 - cos(PI2 * (double)(j - (g << 8)) / 1024.0)));
      acc = __fadd_rn(acc, __fmul_rn(w, w));
    }
    wsq[j] = acc;
  }
  for (int i = idx; i < NMAG; i += stride)
    tprev[i] = make_float2(0.f, 0.f);
  for (int i = idx; i < NBLK * FPAD; i += stride)
    flags[i] = 0u;
}

// ---------------- jax.image.resize bilinear ----------------
__device__ __forceinline__ void lin_taps(float sf, int in, int &i0, int &i1, float &w0, float &w1)
{
  if (sf <= 0.0f)                  { i0 = 0;      i1 = 0;      w0 = 1.0f; w1 = 0.0f; return; }
  if (sf >= (float)(in - 1))       { i0 = in - 1; i1 = in - 1; w0 = 1.0f; w1 = 0.0f; return; }
  i0 = (int)sf; i1 = i0 + 1;
  float x0 = __fsub_rn(sf, (float)i0);
  float a0 = __fsub_rn(1.0f, x0);
  float S  = __fadd_rn(a0, x0);
  w0 = __fdiv_rn(a0, S);
  w1 = __fdiv_rn(x0, S);
}

__device__ __forceinline__ float sf_H1(int H) {
  return __fadd_rn(__fmul_rn(__fadd_rn((float)H, 0.5f), 0.25f), -0.5f);
}
__device__ __forceinline__ float sf_W1(int W) {
  return __fadd_rn(__fmul_rn(__fadd_rn((float)W, 0.5f), 0.125f), -0.5f);
}
__device__ __forceinline__ float sf_H2(int K) {
  const float inv32 = (float)(1.0 / 4.0078125);
  return __fadd_rn(__fmul_rn(__fadd_rn((float)K, 0.5f), inv32), -0.5f);
}

__device__ __forceinline__ float fs_at(const float* __restrict__ pb, int H, int W)
{
  int r0, r1; float u0, u1;
  lin_taps(sf_H1(H), GH, r0, r1, u0, u1);
  int c0, c1; float v0, v1;
  lin_taps(sf_W1(W), GW, c0, c1, v0, v1);
  float t0 = __fmaf_rn(u1, pb[r1 * GW + c0], __fmul_rn(u0, pb[r0 * GW + c0]));
  float t1 = __fmaf_rn(u1, pb[r1 * GW + c1], __fmul_rn(u0, pb[r0 * GW + c1]));
  return __fmaf_rn(v1, t1, __fmul_rn(v0, t0));
}

__global__ __launch_bounds__(256) void k_fullspec(const float* __restrict__ p, float* __restrict__ fs)
{
  int idx = blockIdx.x * 256 + threadIdx.x;
  if (idx >= BATCH * FH * FW) return;
  int b = idx >> 16;
  int h = (idx >> 9) & (FH - 1);
  int w = idx & (FW - 1);
  fs[idx] = fs_at(p + b * (GH * GW), h, w);
}

__global__ __launch_bounds__(256) void k_mag(const float* __restrict__ p, float* __restrict__ mag)
{
  int idx = blockIdx.x * 256 + threadIdx.x;
  if (idx >= NMAG) return;
  int b = idx / (NW * NFREQ);
  int rem = idx - b * (NW * NFREQ);
  int f = rem / NFREQ;
  int k = rem - f * NFREQ;
  const float* pb = p + b * (GH * GW);
  int h0, h1; float wa, wb;
  lin_taps(sf_H2(k), FH, h0, h1, wa, wb);
  float fs0 = fs_at(pb, h0, f);
  float fs1 = fs_at(pb, h1, f);
  float P0 = __fmul_rn(__fmul_rn(fs0, fs0), 100.0f);
  float P1 = __fmul_rn(__fmul_rn(fs1, fs1), 100.0f);
  float lin = __fmaf_rn(wb, P1, __fmul_rn(wa, P0));
  mag[idx] = __fsqrt_rn(fmaxf(lin, 0.0f));
}

__global__ __launch_bounds__(256) void k_phase(float2* __restrict__ ang)
{
  int idx = blockIdx.x * 256 + threadIdx.x;
  if (idx >= NMAG) return;
  int b = idx / (NW * NFREQ);
  int rem = idx - b * (NW * NFREQ);
  int f = rem / NFREQ;
  int k = rem - f * NFREQ;
  u32 cnt = (u32)(b * (NFREQ * NW) + k * NW + f);
  u32 w0, w1;
  threefry2(0u, cnt, w0, w1);
  u32 bits = w0 ^ w1;
  float u = __uint_as_float((bits >> 9) | 0x3f800000u) - 1.0f;
  float th = __fmul_rn((float)6.283185307179586, u);
  double thd = (double)th;
  ang[idx] = make_float2((float)cos(thd), (float)sin(thd));
}

// ---------------- 512-pt FFT: radix-8^3 Stockham, ONE WAVE per transform ----------------
__device__ __forceinline__ float2 cadd2(float2 a, float2 b){ return make_float2(a.x+b.x, a.y+b.y); }
__device__ __forceinline__ float2 csub2(float2 a, float2 b){ return make_float2(a.x-b.x, a.y-b.y); }

template<bool INV>
__device__ __forceinline__ float2 twmul(float2 a, float2 w)
{
  float wy = INV ? -w.y : w.y;
  return make_float2(a.x*w.x - a.y*wy, a.x*wy + a.y*w.x);
}

template<bool INV>
__device__ __forceinline__ void bfly8(float2 x0, float2 x1, float2 x2, float2 x3,
                                      float2 x4, float2 x5, float2 x6, float2 x7,
                                      float2 &Y0, float2 &Y1, float2 &Y2, float2 &Y3,
                                      float2 &Y4, float2 &Y5, float2 &Y6, float2 &Y7)
{
  const float c = 0.70710678118654752440f;
  float2 u0 = cadd2(x0,x4), u1 = cadd2(x1,x5), u2 = cadd2(x2,x6), u3 = cadd2(x3,x7);
  float2 d0 = csub2(x0,x4), d1 = csub2(x1,x5), d2 = csub2(x2,x6), d3 = csub2(x3,x7);
  float2 w1, w2, w3;
  if (!INV) {
    w1 = make_float2(c*(d1.x + d1.y), c*(d1.y - d1.x));   // x w8^1 = (c,-c)
    w2 = make_float2(d2.y, -d2.x);                        // x (-i)
    w3 = make_float2(c*(d3.y - d3.x), -c*(d3.x + d3.y));  // x w8^3 = (-c,-c)
  } else {
    w1 = make_float2(c*(d1.x - d1.y), c*(d1.x + d1.y));   // x (c,c)
    w2 = make_float2(-d2.y, d2.x);                        // x (+i)
    w3 = make_float2(-c*(d3.x + d3.y), c*(d3.x - d3.y));  // x (-c,c)
  }
  float2 s0 = cadd2(u0,u2), s1 = cadd2(u1,u3), s2 = csub2(u0,u2);
  float2 e13 = csub2(u1,u3);
  float2 s3 = INV ? make_float2(-e13.y, e13.x) : make_float2(e13.y, -e13.x);
  float2 r0 = cadd2(d0,w2), r1 = cadd2(w1,w3), r2 = csub2(d0,w2);
  float2 e57 = csub2(w1,w3);
  float2 r3 = INV ? make_float2(-e57.y, e57.x) : make_float2(e57.y, -e57.x);
  Y0 = cadd2(s0,s1); Y4 = csub2(s0,s1);
  Y2 = cadd2(s2,s3); Y6 = csub2(s2,s3);
  Y1 = cadd2(r0,r1); Y5 = csub2(r0,r1);
  Y3 = cadd2(r2,r3); Y7 = csub2(r2,r3);
}

// stage 0: inputs in registers, twiddle base = t, write slots 8t+k
template<bool INV>
__device__ __forceinline__ void stage0_regs(float2* __restrict__ A, const float2* __restrict__ tw, int t,
    float2 x0, float2 x1, float2 x2, float2 x3, float2 x4, float2 x5, float2 x6, float2 x7)
{
  float2 Y0,Y1,Y2,Y3,Y4,Y5,Y6,Y7;
  bfly8<INV>(x0,x1,x2,x3,x4,x5,x6,x7, Y0,Y1,Y2,Y3,Y4,Y5,Y6,Y7);
  int ob = 8 * t;
  A[SL(ob + 0)] = Y0;
  A[SL(ob + 1)] = twmul<INV>(Y1, tw[t]);
  A[SL(ob + 2)] = twmul<INV>(Y2, tw[2 * t]);
  A[SL(ob + 3)] = twmul<INV>(Y3, tw[3 * t]);
  A[SL(ob + 4)] = twmul<INV>(Y4, tw[4 * t]);
  A[SL(ob + 5)] = twmul<INV>(Y5, tw[5 * t]);
  A[SL(ob + 6)] = twmul<INV>(Y6, tw[6 * t]);
  A[SL(ob + 7)] = twmul<INV>(Y7, tw[7 * t]);
}

// stage 1 (L=8): in-place LDS->LDS, twiddle base = 8p, write slots q+64p+8k
template<bool INV>
__device__ __forceinline__ void stage_mid(float2* __restrict__ A, const float2* __restrict__ tw, int t)
{
  float2 x0 = A[SL(t)],       x1 = A[SL(t + 64)],  x2 = A[SL(t + 128)], x3 = A[SL(t + 192)];
  float2 x4 = A[SL(t + 256)], x5 = A[SL(t + 320)], x6 = A[SL(t + 384)], x7 = A[SL(t + 448)];
  float2 Y0,Y1,Y2,Y3,Y4,Y5,Y6,Y7;
  bfly8<INV>(x0,x1,x2,x3,x4,x5,x6,x7, Y0,Y1,Y2,Y3,Y4,Y5,Y6,Y7);
  WAVEFENCE();
  int p = t >> 3, q = t & 7;
  int base = 8 * p;
  int ob = q + 64 * p;
  A[SL(ob)]      = Y0;
  A[SL(ob + 8)]  = twmul<INV>(Y1, tw[base]);
  A[SL(ob + 16)] = twmul<INV>(Y2, tw[2 * base]);
  A[SL(ob + 24)] = twmul<INV>(Y3, tw[3 * base]);
  A[SL(ob + 32)] = twmul<INV>(Y4, tw[4 * base]);
  A[SL(ob + 40)] = twmul<INV>(Y5, tw[5 * base]);
  A[SL(ob + 48)] = twmul<INV>(Y6, tw[6 * base]);
  A[SL(ob + 56)] = twmul<INV>(Y7, tw[7 * base]);
}

// stage 2 (L=64, base=0): lane-local in-place, result natural order A[t+64k]
template<bool INV>
__device__ __forceinline__ void stage_last_lds(float2* __restrict__ A, int t)
{
  float2 x0 = A[SL(t)],       x1 = A[SL(t + 64)],  x2 = A[SL(t + 128)], x3 = A[SL(t + 192)];
  float2 x4 = A[SL(t + 256)], x5 = A[SL(t + 320)], x6 = A[SL(t + 384)], x7 = A[SL(t + 448)];
  float2 Y0,Y1,Y2,Y3,Y4,Y5,Y6,Y7;
  bfly8<INV>(x0,x1,x2,x3,x4,x5,x6,x7, Y0,Y1,Y2,Y3,Y4,Y5,Y6,Y7);
  WAVEFENCE();
  A[SL(t)]       = Y0; A[SL(t + 64)]  = Y1; A[SL(t + 128)] = Y2; A[SL(t + 192)] = Y3;
  A[SL(t + 256)] = Y4; A[SL(t + 320)] = Y5; A[SL(t + 384)] = Y6; A[SL(t + 448)] = Y7;
}

// stage 2 -> registers (inverse tail): Yk = time point t+64k
template<bool INV>
__device__ __forceinline__ void stage_last_regs(const float2* __restrict__ A, int t,
    float2 &Y0, float2 &Y1, float2 &Y2, float2 &Y3, float2 &Y4, float2 &Y5, float2 &Y6, float2 &Y7)
{
  float2 x0 = A[SL(t)],       x1 = A[SL(t + 64)],  x2 = A[SL(t + 128)], x3 = A[SL(t + 192)];
  float2 x4 = A[SL(t + 256)], x5 = A[SL(t + 320)], x6 = A[SL(t + 384)], x7 = A[SL(t + 448)];
  bfly8<INV>(x0,x1,x2,x3,x4,x5,x6,x7, Y0,Y1,Y2,Y3,Y4,Y5,Y6,Y7);
}

// momentum phase update, tprev in GLOBAL (fallback path); writes angle to LDS slot
__device__ __forceinline__ void upd_bin(float2* __restrict__ prow, float2* __restrict__ A,
                                        int k, double rx, double ry, float cf)
{
  float rxf = (float)rx, ryf = (float)ry;
  float2 pv = prow[k];
  float ax = __fsub_rn(rxf, __fmul_rn(pv.x, cf));
  float ay = __fsub_rn(ryf, __fmul_rn(pv.y, cf));
  double dx = (double)ax, dy = (double)ay;
  float d = (float)sqrt(dx * dx + dy * dy);
  float d2 = __fadd_rn(d, 1e-16f);
  float inv = __fdiv_rn(1.0f, d2);
  int slot = (k == 512) ? (WSL - 1) : SL(k);
  A[slot] = make_float2(__fmul_rn(ax, inv), __fmul_rn(ay, inv));
  prow[k] = make_float2(rxf, ryf);
}

// momentum phase update, tprev in a REGISTER (persistent path)
__device__ __forceinline__ void upd_reg(float2 &tprev, float2* __restrict__ A,
                                        int slot, double rx, double ry, float cf)
{
  float rxf = (float)rx, ryf = (float)ry;
  float ax = __fsub_rn(rxf, __fmul_rn(tprev.x, cf));
  float ay = __fsub_rn(ryf, __fmul_rn(tprev.y, cf));
  double dx = (double)ax, dy = (double)ay;
  float d = (float)sqrt(dx * dx + dy * dy);
  float d2 = __fadd_rn(d, 1e-16f);
  float inv = __fdiv_rn(1.0f, d2);
  A[slot] = make_float2(__fmul_rn(ax, inv), __fmul_rn(ay, inv));
  tprev = make_float2(rxf, ryf);
}

// ---------------- initial ISTFT: wave-per-frame ----------------
__global__ __launch_bounds__(256) void k_istft(const float* __restrict__ mag, const float2* __restrict__ ang,
                                               float* __restrict__ frames,
                                               const float2* __restrict__ tw512f,
                                               const double2* __restrict__ twh,
                                               const float* __restrict__ win)
{
  __shared__ float2 ldsA[4 * WSL];
  __shared__ float2 twl[512];
  int tid = threadIdx.x;
  for (int i = tid; i < 512; i += 256) twl[i] = tw512f[i];
  __syncthreads();

  int wv = tid >> 6;
  int t  = tid & 63;
  int bf = (blockIdx.x << 2) + wv;
  float2* A = ldsA + wv * WSL;
  const float*  mrow = mag + bf * NFREQ;
  const float2* arow = ang + bf * NFREQ;

  // Hermitian pack straight into registers (points k = t + 64j)
  float2 z0, z1, z2, z3, z4, z5, z6, z7;
#define PACKG(j, zj) { \
    int k = t + 64 * j; \
    if (k == 0) { \
      float m1 = mrow[0];   float2 a1 = arow[0]; \
      float m2 = mrow[512]; float2 a2 = arow[512]; \
      float S1x = __fmul_rn(m1, a1.x); \
      float S2x = __fmul_rn(m2, a2.x); \
      zj = make_float2((float)(0.5 * ((double)S1x + (double)S2x)), \
                       (float)(0.5 * ((double)S1x - (double)S2x))); \
    } else { \
      int k2 = 512 - k; \
      float m1 = mrow[k];  float2 a1 = arow[k]; \
      float m2 = mrow[k2]; float2 a2 = arow[k2]; \
      float S1x = __fmul_rn(m1, a1.x), S1y = __fmul_rn(m1, a1.y); \
      float S2x = __fmul_rn(m2, a2.x), S2y = __fmul_rn(m2, a2.y); \
      double Xex = 0.5 * ((double)S1x + (double)S2x); \
      double Xey = 0.5 * ((double)S1y - (double)S2y); \
      double Dx  = 0.5 * ((double)S1x - (double)S2x); \
      double Dy  = 0.5 * ((double)S1y + (double)S2y); \
      double2 w = twh[k]; \
      double ux = w.x * Dx + w.y * Dy; \
      double uy = w.x * Dy - w.y * Dx; \
      zj = make_float2((float)(Xex - uy), (float)(Xey + ux)); \
    } }
  PACKG(0, z0) PACKG(1, z1) PACKG(2, z2) PACKG(3, z3)
  PACKG(4, z4) PACKG(5, z5) PACKG(6, z6) PACKG(7, z7)

  stage0_regs<true>(A, twl, t, z0, z1, z2, z3, z4, z5, z6, z7);
  WAVEFENCE();
  stage_mid<true>(A, twl, t);
  WAVEFENCE();
  float2 y0, y1, y2, y3, y4, y5, y6, y7;
  stage_last_regs<true>(A, t, y0, y1, y2, y3, y4, y5, y6, y7);

  const float sc = 1.0f / 512.0f;
  const float2* win2 = (const float2*)win;
  float2* frow2 = (float2*)(frames + bf * NFFT);
#define STOREF(k, yk) { int m = t + 64 * k; float2 wv2 = win2[m]; \
    frow2[m] = make_float2(__fmul_rn(__fmul_rn(yk.x, sc), wv2.x), \
                           __fmul_rn(__fmul_rn(yk.y, sc), wv2.y)); }
  STOREF(0, y0) STOREF(1, y1) STOREF(2, y2) STOREF(3, y3)
  STOREF(4, y4) STOREF(5, y5) STOREF(6, y6) STOREF(7, y7)
}

// f32 OLA sample at wsq-coordinate j (normal cached loads)
__device__ __forceinline__ float sig_sample(const float* __restrict__ fb, const float* __restrict__ wsq, int j)
{
  int gmax = j >> 8; if (gmax > NW - 1) gmax = NW - 1;
  int gmin = (j >= NFFT) ? ((j - (NFFT - 1) + 255) >> 8) : 0;
  float acc = 0.f;
  for (int g = gmin; g <= gmax; ++g)
    acc = __fadd_rn(acc, fb[g * NFFT + (j - (g << 8))]);
  float wv = wsq[j];
  return __fdiv_rn(acc, wv > 1e-11f ? wv : 1.0f);
}

// agent-scope coherent (L2-bypassing) load — frames taps in the persistent loop
__device__ __forceinline__ float ld_sc(const float* p)
{
  return __hip_atomic_load(p, __ATOMIC_RELAXED, __HIP_MEMORY_SCOPE_AGENT);
}

__device__ __forceinline__ float sig_sample_sc(const float* __restrict__ fb, const float* __restrict__ wsq, int j)
{
  int gmax = j >> 8; if (gmax > NW - 1) gmax = NW - 1;
  int gmin = (j >= NFFT) ? ((j - (NFFT - 1) + 255) >> 8) : 0;
  float acc = 0.f;
  for (int g = gmin; g <= gmax; ++g)
    acc = __fadd_rn(acc, ld_sc(&fb[g * NFFT + (j - (g << 8))]));
  float wv = wsq[j];
  return __fdiv_rn(acc, wv > 1e-11f ? wv : 1.0f);
}

// ================= FALLBACK: per-iteration fused kernel (R6, verified) =================
__global__ __launch_bounds__(256) void k_fused(const float* __restrict__ frames_in,
                                               const float* __restrict__ wsq,
                                               const float* __restrict__ win,
                                               const float2* __restrict__ tw512f,
                                               const double2* __restrict__ twh,
                                               const float* __restrict__ mag,
                                               float2* __restrict__ tprev,
                                               float* __restrict__ frames_out)
{
  __shared__ float2 ldsA[4 * WSL];
  __shared__ float2 twl[512];
  __shared__ float2 xpL2[XSPAN / 2];
  float* xpL = (float*)xpL2;
  int tid = threadIdx.x;
  for (int i = tid; i < 512; i += 256) twl[i] = tw512f[i];

  int bf0 = blockIdx.x << 2;
  int b  = bf0 >> 9;
  int f0 = bf0 & (NW - 1);
  const float* fb = frames_in + b * (NW * NFFT);
  int xbase = f0 * HOP;
#pragma unroll
  for (int c = 0; c < XSPAN / 256; ++c) {
    int s = tid + 256 * c;
    int j = xbase + s;
    int n = j - 512;
    if (n < 0) n = -n;
    if (n >= SIGLEN) n = 2 * SIGLEN - 2 - n;
    xpL[s] = sig_sample(fb, wsq, n + 512);
  }
  __syncthreads();

  int wv = tid >> 6;
  int t  = tid & 63;
  int bf = bf0 + wv;
  float2* A = ldsA + wv * WSL;
  const float2* win2 = (const float2*)win;

  const float2* xrow2 = (const float2*)(xpL + wv * HOP);
  float2 x0, x1, x2, x3, x4, x5, x6, x7;
#define LOADXF(j, xj) { float2 xv = xrow2[t + 64 * j]; float2 wv2 = win2[t + 64 * j]; \
    xj = make_float2(__fmul_rn(xv.x, wv2.x), __fmul_rn(xv.y, wv2.y)); }
  LOADXF(0, x0) LOADXF(1, x1) LOADXF(2, x2) LOADXF(3, x3)
  LOADXF(4, x4) LOADXF(5, x5) LOADXF(6, x6) LOADXF(7, x7)
  stage0_regs<false>(A, twl, t, x0, x1, x2, x3, x4, x5, x6, x7);
  WAVEFENCE();
  stage_mid<false>(A, twl, t);
  WAVEFENCE();
  stage_last_lds<false>(A, t);
  WAVEFENCE();

  float2* prow = tprev + bf * NFREQ;
  const float cf = (float)(0.99 / 1.99);
#pragma unroll
  for (int j = 0; j < 4; ++j) {
    int k = t + 64 * j;
    if (k == 0) {
      float2 Z0 = A[SL(0)];
      double rx0 = (double)Z0.x + (double)Z0.y;
      double rx5 = (double)Z0.x - (double)Z0.y;
      upd_bin(prow, A, 0,   rx0, 0.0, cf);
      upd_bin(prow, A, 512, rx5, 0.0, cf);
    } else {
      int kc = 512 - k;
      float2 Zk = A[SL(k)];
      float2 Zc = A[SL(kc)];
      double Xex = 0.5 * ((double)Zk.x + (double)Zc.x);
      double Xey = 0.5 * ((double)Zk.y - (double)Zc.y);
      double Gx  = 0.5 * ((double)Zk.x - (double)Zc.x);
      double Gy  = 0.5 * ((double)Zk.y + (double)Zc.y);
      double2 w = twh[k];
      double P = w.x * Gy + w.y * Gx;
      double Q = w.y * Gy - w.x * Gx;
      upd_bin(prow, A, k,  Xex + P, Xey + Q, cf);
      upd_bin(prow, A, kc, Xex - P, Q - Xey, cf);
    }
  }
  if (t == 0) {
    float2 Zk = A[SL(256)];
    double Xex = 0.5 * ((double)Zk.x + (double)Zk.x);
    double Gy  = 0.5 * ((double)Zk.y + (double)Zk.y);
    double2 w = twh[256];
    double P = w.x * Gy;
    double Q = w.y * Gy;
    upd_bin(prow, A, 256, Xex + P, Q, cf);
  }
  WAVEFENCE();

  const float* mrow = mag + bf * NFREQ;
  float2 z0, z1, z2, z3, z4, z5, z6, z7;
#define PACKLF(j, zj) { \
    int k = t + 64 * j; \
    if (k == 0) { \
      float m1 = mrow[0];   float2 a1 = A[SL(0)]; \
      float m2 = mrow[512]; float2 a2 = A[WSL - 1]; \
      float S1x = __fmul_rn(m1, a1.x); \
      float S2x = __fmul_rn(m2, a2.x); \
      zj = make_float2((float)(0.5 * ((double)S1x + (double)S2x)), \
                       (float)(0.5 * ((double)S1x - (double)S2x))); \
    } else { \
      int k2 = 512 - k; \
      float m1 = mrow[k];  float2 a1 = A[SL(k)]; \
      float m2 = mrow[k2]; float2 a2 = A[SL(k2)]; \
      float S1x = __fmul_rn(m1, a1.x), S1y = __fmul_rn(m1, a1.y); \
      float S2x = __fmul_rn(m2, a2.x), S2y = __fmul_rn(m2, a2.y); \
      double Xex = 0.5 * ((double)S1x + (double)S2x); \
      double Xey = 0.5 * ((double)S1y - (double)S2y); \
      double Dx  = 0.5 * ((double)S1x - (double)S2x); \
      double Dy  = 0.5 * ((double)S1y + (double)S2y); \
      double2 w = twh[k]; \
      double ux = w.x * Dx + w.y * Dy; \
      double uy = w.x * Dy - w.y * Dx; \
      zj = make_float2((float)(Xex - uy), (float)(Xey + ux)); \
    } }
  PACKLF(0, z0) PACKLF(1, z1) PACKLF(2, z2) PACKLF(3, z3)
  PACKLF(4, z4) PACKLF(5, z5) PACKLF(6, z6) PACKLF(7, z7)
  WAVEFENCE();

  stage0_regs<true>(A, twl, t, z0, z1, z2, z3, z4, z5, z6, z7);
  WAVEFENCE();
  stage_mid<true>(A, twl, t);
  WAVEFENCE();
  float2 y0, y1, y2, y3, y4, y5, y6, y7;
  stage_last_regs<true>(A, t, y0, y1, y2, y3, y4, y5, y6, y7);

  const float sc = 1.0f / 512.0f;
  float2* frow2 = (float2*)(frames_out + bf * NFFT);
  STOREF(0, y0) STOREF(1, y1) STOREF(2, y2) STOREF(3, y3)
  STOREF(4, y4) STOREF(5, y5) STOREF(6, y6) STOREF(7, y7)
}

// ================= PERSISTENT loop with NEIGHBOR-ONLY flag sync =================
// Block bi's staging window covers frames [f0-3, f0+6] -> deps = {bi-1, bi, bi+1} within
// the same batch (verified incl. reflection at both edges). frames traffic goes through
// agent-scope (L2-bypassing) loads/stores -> coherent at L3, no cache flushes needed.
// Release = __syncthreads (drains every wave's vmcnt -> sc-stores at coherence point),
// then a relaxed flag store. <=2 pollers per 64B flag line -> no spin storm.
__global__ __launch_bounds__(256, 4) void k_loop(float* __restrict__ framesA,
                                                 float* __restrict__ framesB,
                                                 const float* __restrict__ wsq,
                                                 const float* __restrict__ win,
                                                 const float2* __restrict__ tw512f,
                                                 const double2* __restrict__ twh,
                                                 const float* __restrict__ mag,
                                                 u32* __restrict__ flags)
{
  __shared__ float2 ldsA[4 * WSL];            // 18432 B
  __shared__ float2 twl[512];                 //  4096 B
  __shared__ float2 xpL2[XSPAN / 2];          //  7168 B   (total 29696 B)
  float* xpL = (float*)xpL2;

  int tid = threadIdx.x;
  int wv = tid >> 6;
  int t  = tid & 63;
  int bf0 = blockIdx.x << 2;
  int b  = bf0 >> 9;
  int f0 = bf0 & (NW - 1);
  int bf = bf0 + wv;
  float2* A = ldsA + wv * WSL;
  const float2* win2 = (const float2*)win;

  int self = blockIdx.x;
  int bi   = self & 127;                       // block index within batch
  int nbL  = (bi > 0)   ? self - 1 : self;
  int nbR  = (bi < 127) ? self + 1 : self;

  for (int i = tid; i < 512; i += 256) twl[i] = tw512f[i];

  // mag row -> 16 registers (constant across iterations)
  const float* mrow = mag + bf * NFREQ;
  float mg0 = mrow[t],       mg1 = mrow[t + 64],  mg2 = mrow[t + 128], mg3 = mrow[t + 192];
  float mg4 = mrow[t + 256], mg5 = mrow[t + 320], mg6 = mrow[t + 384], mg7 = mrow[t + 448];
  float mh0 = mrow[512 - t], mh1 = mrow[448 - t], mh2 = mrow[384 - t], mh3 = mrow[320 - t];
  float mh4 = mrow[256 - t], mh5 = mrow[192 - t], mh6 = mrow[128 - t], mh7 = mrow[64 - t];

  // persistent tprev registers
  float2 tp0 = make_float2(0.f, 0.f), tp1 = tp0, tp2 = tp0, tp3 = tp0;
  float2 tq0 = tp0, tq1 = tp0, tq2 = tp0, tq3 = tp0;
  float2 tr  = tp0;

  const float cf = (float)(0.99 / 1.99);
  const float sc = 1.0f / 512.0f;
  int xbase = f0 * HOP;

  for (int it = 0; it < NITER; ++it) {
    const float* fin  = (it & 1) ? framesB : framesA;
    float*       fout = (it & 1) ? framesA : framesB;
    const float* fb = fin + b * (NW * NFFT);

    // ---- block-shared OLA staging via coherent taps (bit-identical arithmetic) ----
#pragma unroll
    for (int c = 0; c < XSPAN / 256; ++c) {
      int s = tid + 256 * c;
      int j = xbase + s;
      int n = j - 512;
      if (n < 0) n = -n;
      if (n >= SIGLEN) n = 2 * SIGLEN - 2 - n;
      xpL[s] = (it == 0) ? sig_sample(fb, wsq, n + 512)      // iter 0: k_istft output, cached OK
                         : sig_sample_sc(fb, wsq, n + 512);  // later: neighbors' sc-stores
    }
    __syncthreads();

    // ---- forward ----
    const float2* xrow2 = (const float2*)(xpL + wv * HOP);
    float2 x0, x1, x2, x3, x4, x5, x6, x7;
#define LOADX2(j, xj) { float2 xv = xrow2[t + 64 * j]; float2 wv2 = win2[t + 64 * j]; \
    xj = make_float2(__fmul_rn(xv.x, wv2.x), __fmul_rn(xv.y, wv2.y)); }
    LOADX2(0, x0) LOADX2(1, x1) LOADX2(2, x2) LOADX2(3, x3)
    LOADX2(4, x4) LOADX2(5, x5) LOADX2(6, x6) LOADX2(7, x7)
    stage0_regs<false>(A, twl, t, x0, x1, x2, x3, x4, x5, x6, x7);
    WAVEFENCE();
    stage_mid<false>(A, twl, t);
    WAVEFENCE();
    stage_last_lds<false>(A, t);
    WAVEFENCE();

    // ---- unpack + momentum update into register tprev ----
#define UPDP2(j, tpj, tqj) { \
      int k = t + 64 * (j); \
      if ((j) == 0 && k == 0) { \
        float2 Z0 = A[SL(0)]; \
        double rx0 = (double)Z0.x + (double)Z0.y; \
        double rx5 = (double)Z0.x - (double)Z0.y; \
        upd_reg(tpj, A, SL(0),   rx0, 0.0, cf); \
        upd_reg(tqj, A, WSL - 1, rx5, 0.0, cf); \
      } else { \
        int kc = 512 - k; \
        float2 Zk = A[SL(k)]; \
        float2 Zc = A[SL(kc)]; \
        double Xex = 0.5 * ((double)Zk.x + (double)Zc.x); \
        double Xey = 0.5 * ((double)Zk.y - (double)Zc.y); \
        double Gx  = 0.5 * ((double)Zk.x - (double)Zc.x); \
        double Gy  = 0.5 * ((double)Zk.y + (double)Zc.y); \
        double2 w = twh[k]; \
        double P = w.x * Gy + w.y * Gx; \
        double Q = w.y * Gy - w.x * Gx; \
        upd_reg(tpj, A, SL(k),  Xex + P, Xey + Q, cf); \
        upd_reg(tqj, A, SL(kc), Xex - P, Q - Xey, cf); \
      } }
    UPDP2(0, tp0, tq0)
    UPDP2(1, tp1, tq1)
    UPDP2(2, tp2, tq2)
    UPDP2(3, tp3, tq3)
    if (t == 0) {
      float2 Zk = A[SL(256)];
      double Xex = 0.5 * ((double)Zk.x + (double)Zk.x);
      double Gy  = 0.5 * ((double)Zk.y + (double)Zk.y);
      double2 w = twh[256];
      double P = w.x * Gy;
      double Q = w.y * Gy;
      upd_reg(tr, A, SL(256), Xex + P, Q, cf);
    }
    WAVEFENCE();

    // ---- inverse: Hermitian pack (register mag x LDS angles) ----
    float2 z0, z1, z2, z3, z4, z5, z6, z7;
#define PACKL2(j, zj, mgj, mhj) { \
      int k = t + 64 * j; \
      if (k == 0) { \
        float2 a1 = A[SL(0)]; \
        float2 a2 = A[WSL - 1]; \
        float S1x = __fmul_rn(mgj, a1.x); \
        float S2x = __fmul_rn(mhj, a2.x); \
        zj = make_float2((float)(0.5 * ((double)S1x + (double)S2x)), \
                         (float)(0.5 * ((double)S1x - (double)S2x))); \
      } else { \
        int k2 = 512 - k; \
        float2 a1 = A[SL(k)]; \
        float2 a2 = A[SL(k2)]; \
        float S1x = __fmul_rn(mgj, a1.x), S1y = __fmul_rn(mgj, a1.y); \
        float S2x = __fmul_rn(mhj, a2.x), S2y = __fmul_rn(mhj, a2.y); \
        double Xex = 0.5 * ((double)S1x + (double)S2x); \
        double Xey = 0.5 * ((double)S1y - (double)S2y); \
        double Dx  = 0.5 * ((double)S1x - (double)S2x); \
        double Dy  = 0.5 * ((double)S1y + (double)S2y); \
        double2 w = twh[k]; \
        double ux = w.x * Dx + w.y * Dy; \
        double uy = w.x * Dy - w.y * Dx; \
        zj = make_float2((float)(Xex - uy), (float)(Xey + ux)); \
      } }
    PACKL2(0, z0, mg0, mh0) PACKL2(1, z1, mg1, mh1) PACKL2(2, z2, mg2, mh2) PACKL2(3, z3, mg3, mh3)
    PACKL2(4, z4, mg4, mh4) PACKL2(5, z5, mg5, mh5) PACKL2(6, z6, mg6, mh6) PACKL2(7, z7, mg7, mh7)
    WAVEFENCE();

    stage0_regs<true>(A, twl, t, z0, z1, z2, z3, z4, z5, z6, z7);
    WAVEFENCE();
    stage_mid<true>(A, twl, t);
    WAVEFENCE();
    float2 y0, y1, y2, y3, y4, y5, y6, y7;
    stage_last_regs<true>(A, t, y0, y1, y2, y3, y4, y5, y6, y7);

    // ---- store frames via agent-scope (coherent) stores ----
    float2* frow2 = (float2*)(fout + bf * NFFT);
#define STOREF_SC(k, yk) { int m = t + 64 * k; float2 wv2 = win2[m]; \
    float2 vv = make_float2(__fmul_rn(__fmul_rn(yk.x, sc), wv2.x), \
                            __fmul_rn(__fmul_rn(yk.y, sc), wv2.y)); \
    unsigned long long uu; __builtin_memcpy(&uu, &vv, 8); \
    __hip_atomic_store((unsigned long long*)&frow2[m], uu, __ATOMIC_RELAXED, __HIP_MEMORY_SCOPE_AGENT); }
    STOREF_SC(0, y0) STOREF_SC(1, y1) STOREF_SC(2, y2) STOREF_SC(3, y3)
    STOREF_SC(4, y4) STOREF_SC(5, y5) STOREF_SC(6, y6) STOREF_SC(7, y7)

    if (it + 1 < NITER) {
      __syncthreads();   // every wave drains vmcnt -> all sc-stores at coherence point
      if (tid == 0) {
        __hip_atomic_store(&flags[self * FPAD], (u32)(it + 1), __ATOMIC_RELAXED, __HIP_MEMORY_SCOPE_AGENT);
        if (nbL != self)
          while (__hip_atomic_load(&flags[nbL * FPAD], __ATOMIC_RELAXED, __HIP_MEMORY_SCOPE_AGENT) <= (u32)it)
            __builtin_amdgcn_s_sleep(8);
        if (nbR != self)
          while (__hip_atomic_load(&flags[nbR * FPAD], __ATOMIC_RELAXED, __HIP_MEMORY_SCOPE_AGENT) <= (u32)it)
            __builtin_amdgcn_s_sleep(8);
      }
      __syncthreads();   // all lanes past the poll; xpL safe to overwrite
    }
  }
}

// ---------------- final OLA -> audio f32 + per-block |max| ----------------
__global__ __launch_bounds__(256) void k_ola(const float* __restrict__ frames, const float* __restrict__ wsq,
                                             float* __restrict__ audio, float* __restrict__ partial)
{
  int idx = blockIdx.x * 256 + threadIdx.x;
  int b  = idx >> 17;
  int nn = idx & (NSAMP - 1);
  float v = 0.f;
  if (nn < SIGLEN)
    v = sig_sample(frames + b * (NW * NFFT), wsq, nn + 512);
  audio[idx] = v;
  __shared__ float red[256];
  red[threadIdx.x] = fabsf(v);
  __syncthreads();
  for (int s = 128; s > 0; s >>= 1) {
    if (threadIdx.x < s) red[threadIdx.x] = fmaxf(red[threadIdx.x], red[threadIdx.x + s]);
    __syncthreads();
  }
  if (threadIdx.x == 0) partial[blockIdx.x] = red[0];
}

constexpr int OLA_BLK_PER_B = NSAMP / 256;   // 512

__global__ __launch_bounds__(256) void k_max2(const float* __restrict__ partial, float* __restrict__ maxbuf)
{
  int b = blockIdx.x;
  float m = 0.f;
  for (int i = threadIdx.x; i < OLA_BLK_PER_B; i += 256)
    m = fmaxf(m, partial[b * OLA_BLK_PER_B + i]);
  __shared__ float red[256];
  red[threadIdx.x] = m;
  __syncthreads();
  for (int s = 128; s > 0; s >>= 1) {
    if (threadIdx.x < s) red[threadIdx.x] = fmaxf(red[threadIdx.x], red[threadIdx.x + s]);
    __syncthreads();
  }
  if (threadIdx.x == 0) maxbuf[b] = red[0];
}

__global__ __launch_bounds__(256) void k_norm(const float* __restrict__ audio, const float* __restrict__ maxbuf,
                                              float* __restrict__ out)
{
  int idx = blockIdx.x * 256 + threadIdx.x;
  int b = idx >> 17;
  float m = fmaxf(maxbuf[b], 1e-8f);
  out[idx] = __fmul_rn(__fdiv_rn(audio[idx], m), 0.9f);
}

extern "C" void kernel_launch(void* const* d_in, const int* in_sizes, int n_in,
                              void* d_out, int out_size, void* d_ws, size_t ws_size,
                              hipStream_t stream)
{
  const float* params = (const float*)d_in[0];
  float* out   = (float*)d_out;
  float* audio_out = out;                   // BATCH*NSAMP
  float* fs        = out + BATCH * NSAMP;   // BATCH*FH*FW (full_spec output)

  float2*  tw512f = (float2*)d_ws;                         // 512
  double2* twh    = (double2*)(tw512f + 512);              // 512
  float2*  ang    = (float2*)(twh + 512);                  // NMAG c64 (initial phases; dead after k_istft)
  float2*  tprev  = ang + NMAG;                            // NMAG c64 (fallback path only)
  float*   framesA= (float*)(tprev + NMAG);                // BATCH*NW*NFFT f32
  float*   mag    = framesA + BATCH * NW * NFFT;           // NMAG f32
  float*   win    = mag + NMAG;                            // NFFT
  float*   wsq    = win + NFFT;                            // TOTAL_LEN
  float*   audio32= wsq + TOTAL_LEN;                       // BATCH*NSAMP
  float*   maxbuf = audio32 + BATCH * NSAMP;               // BATCH
  float*   partial= maxbuf + BATCH;                        // BATCH*OLA_BLK_PER_B
  u32*     flags  = (u32*)(partial + BATCH * OLA_BLK_PER_B); // NBLK*FPAD u32 (64B-padded)
  // frames ping-pong buffer B aliases the dead ang region:
  // NMAG*8 = 16,809,984 B >= BATCH*NW*NFFT*4 = 16,777,216 B; 16B-aligned.
  float*   framesB= (float*)ang;

  k_init<<<512, 256, 0, stream>>>(win, tw512f, twh, wsq, tprev, flags);
  k_fullspec<<<(BATCH * FH * FW) / 256, 256, 0, stream>>>(params, fs);
  k_mag<<<(NMAG + 255) / 256, 256, 0, stream>>>(params, mag);
  k_phase<<<(NMAG + 255) / 256, 256, 0, stream>>>(ang);

  k_istft<<<NBLK, 256, 0, stream>>>(mag, (const float2*)ang, framesA, tw512f, twh, win);

  // persistent loop with neighbor-flag sync; cooperative launch guarantees co-residency.
  // On ANY launch error, fall back to the verified per-iteration path (bit-identical math).
  void* args[] = { (void*)&framesA, (void*)&framesB, (void*)&wsq, (void*)&win,
                   (void*)&tw512f, (void*)&twh, (void*)&mag, (void*)&flags };
  hipError_t ce = hipLaunchCooperativeKernel((const void*)k_loop, dim3(NBLK), dim3(256),
                                             args, 0, stream);
  if (ce != hipSuccess) {
    float* fin  = framesA;
    float* fout = framesB;
    for (int it = 0; it < NITER; ++it) {
      k_fused<<<NBLK, 256, 0, stream>>>(fin, wsq, win, tw512f, twh, mag, tprev, fout);
      float* tmp = fin; fin = fout; fout = tmp;
    }
  }
  // NITER even -> final frames in framesA on both paths
  k_ola<<<(BATCH * NSAMP) / 256, 256, 0, stream>>>(framesA, wsq, audio32, partial);
  k_max2<<<BATCH, 256, 0, stream>>>(partial, maxbuf);
  k_norm<<<(BATCH * NSAMP) / 256, 256, 0, stream>>>(audio32, maxbuf, audio_out);
}

// Round 11
// 966.147 us; speedup vs baseline: 3.2688x; 1.4761x over previous
//
#include <hip/hip_runtime.h>

typedef unsigned int u32;

constexpr int BATCH = 8;
constexpr int GH = 32, GW = 64;
constexpr int FH = 128, FW = 512;
constexpr int NFFT = 1024;
constexpr int HOP = 256;
constexpr int NFREQ = 513;
constexpr int NW = 512;                       // frames per batch
constexpr int SIGLEN = HOP * (NW - 1);        // 130816
constexpr int TOTAL_LEN = NFFT + HOP*(NW-1);  // 131840
constexpr int NITER = 32;
constexpr int NSAMP = 131072;
constexpr int NMAG = BATCH * NW * NFREQ;      // 2101248

// LDS index padding (9/8 stride)
#define SL(i) ((i) + ((i) >> 3))
constexpr int WSL = 576;    // per-wave LDS slots: SL(511)=574, slot 575 = bin-512 home

#define WAVEFENCE() __builtin_amdgcn_wave_barrier()

// ---------------- Threefry-2x32-20, partitionable path (key = (0,1)) ----------------
__device__ __forceinline__ void tf_round(u32 &x0, u32 &x1, int r) {
  x0 += x1;
  x1 = (x1 << r) | (x1 >> (32 - r));
  x1 ^= x0;
}

__device__ __forceinline__ void threefry2(u32 c0, u32 c1, u32 &o0, u32 &o1) {
  const u32 k0 = 0u, k1 = 1u;
  const u32 k2 = 0x1BD11BDAu ^ k0 ^ k1;
  u32 x0 = c0 + k0, x1 = c1 + k1;
  tf_round(x0, x1, 13); tf_round(x0, x1, 15); tf_round(x0, x1, 26); tf_round(x0, x1, 6);
  x0 += k1; x1 += k2 + 1u;
  tf_round(x0, x1, 17); tf_round(x0, x1, 29); tf_round(x0, x1, 16); tf_round(x0, x1, 24);
  x0 += k2; x1 += k0 + 2u;
  tf_round(x0, x1, 13); tf_round(x0, x1, 15); tf_round(x0, x1, 26); tf_round(x0, x1, 6);
  x0 += k0; x1 += k1 + 3u;
  tf_round(x0, x1, 17); tf_round(x0, x1, 29); tf_round(x0, x1, 16); tf_round(x0, x1, 24);
  x0 += k1; x1 += k2 + 4u;
  tf_round(x0, x1, 13); tf_round(x0, x1, 15); tf_round(x0, x1, 26); tf_round(x0, x1, 6);
  x0 += k2; x1 += k0 + 5u;
  o0 = x0; o1 = x1;
}

// ---------------- init ----------------
__global__ __launch_bounds__(256) void k_init(float* __restrict__ win,
                                              float2* __restrict__ tw512f, double2* __restrict__ twh,
                                              float* __restrict__ wsq,
                                              float2* __restrict__ tprev)
{
  int idx = blockIdx.x * 256 + threadIdx.x;
  int stride = gridDim.x * 256;
  const double PI2 = 6.283185307179586476925286766559;
  for (int t = idx; t < NFFT; t += stride)
    win[t] = (float)(0.5 * (1.0 - cos(PI2 * (double)t / 1024.0)));  // _WIN f32
  for (int k = idx; k < 512; k += stride) {
    double th = -PI2 * (double)k / 512.0;
    tw512f[k] = make_float2((float)cos(th), (float)sin(th));  // e^{-2pi i k/512}
    double th2 = -PI2 * (double)k / 1024.0;
    double2 v2; v2.x = cos(th2); v2.y = sin(th2);
    twh[k] = v2;                                      // e^{-2pi i k/1024} (f64 boundary)
  }
  for (int j = idx; j < TOTAL_LEN; j += stride) {
    int gmax = j >> 8; if (gmax > NW - 1) gmax = NW - 1;
    int gmin = (j >= NFFT) ? ((j - (NFFT - 1) + 255) >> 8) : 0;
    float acc = 0.f;
    for (int g = gmin; g <= gmax; ++g) {
      float w = (float)(0.5 * (1.0 - cos(PI2 * (double)(j - (g << 8)) / 1024.0)));
      acc = __fadd_rn(acc, __fmul_rn(w, w));
    }
    wsq[j] = acc;
  }
  for (int i = idx; i < NMAG; i += stride)
    tprev[i] = make_float2(0.f, 0.f);
}

// ---------------- jax.image.resize bilinear ----------------
__device__ __forceinline__ void lin_taps(float sf, int in, int &i0, int &i1, float &w0, float &w1)
{
  if (sf <= 0.0f)                  { i0 = 0;      i1 = 0;      w0 = 1.0f; w1 = 0.0f; return; }
  if (sf >= (float)(in - 1))       { i0 = in - 1; i1 = in - 1; w0 = 1.0f; w1 = 0.0f; return; }
  i0 = (int)sf; i1 = i0 + 1;
  float x0 = __fsub_rn(sf, (float)i0);
  float a0 = __fsub_rn(1.0f, x0);
  float S  = __fadd_rn(a0, x0);
  w0 = __fdiv_rn(a0, S);
  w1 = __fdiv_rn(x0, S);
}

__device__ __forceinline__ float sf_H1(int H) {
  return __fadd_rn(__fmul_rn(__fadd_rn((float)H, 0.5f), 0.25f), -0.5f);
}
__device__ __forceinline__ float sf_W1(int W) {
  return __fadd_rn(__fmul_rn(__fadd_rn((float)W, 0.5f), 0.125f), -0.5f);
}
__device__ __forceinline__ float sf_H2(int K) {
  const float inv32 = (float)(1.0 / 4.0078125);
  return __fadd_rn(__fmul_rn(__fadd_rn((float)K, 0.5f), inv32), -0.5f);
}

__device__ __forceinline__ float fs_at(const float* __restrict__ pb, int H, int W)
{
  int r0, r1; float u0, u1;
  lin_taps(sf_H1(H), GH, r0, r1, u0, u1);
  int c0, c1; float v0, v1;
  lin_taps(sf_W1(W), GW, c0, c1, v0, v1);
  float t0 = __fmaf_rn(u1, pb[r1 * GW + c0], __fmul_rn(u0, pb[r0 * GW + c0]));
  float t1 = __fmaf_rn(u1, pb[r1 * GW + c1], __fmul_rn(u0, pb[r0 * GW + c1]));
  return __fmaf_rn(v1, t1, __fmul_rn(v0, t0));
}

__global__ __launch_bounds__(256) void k_fullspec(const float* __restrict__ p, float* __restrict__ fs)
{
  int idx = blockIdx.x * 256 + threadIdx.x;
  if (idx >= BATCH * FH * FW) return;
  int b = idx >> 16;
  int h = (idx >> 9) & (FH - 1);
  int w = idx & (FW - 1);
  fs[idx] = fs_at(p + b * (GH * GW), h, w);
}

__global__ __launch_bounds__(256) void k_mag(const float* __restrict__ p, float* __restrict__ mag)
{
  int idx = blockIdx.x * 256 + threadIdx.x;
  if (idx >= NMAG) return;
  int b = idx / (NW * NFREQ);
  int rem = idx - b * (NW * NFREQ);
  int f = rem / NFREQ;
  int k = rem - f * NFREQ;
  const float* pb = p + b * (GH * GW);
  int h0, h1; float wa, wb;
  lin_taps(sf_H2(k), FH, h0, h1, wa, wb);
  float fs0 = fs_at(pb, h0, f);
  float fs1 = fs_at(pb, h1, f);
  float P0 = __fmul_rn(__fmul_rn(fs0, fs0), 100.0f);
  float P1 = __fmul_rn(__fmul_rn(fs1, fs1), 100.0f);
  float lin = __fmaf_rn(wb, P1, __fmul_rn(wa, P0));
  mag[idx] = __fsqrt_rn(fmaxf(lin, 0.0f));
}

__global__ __launch_bounds__(256) void k_phase(float2* __restrict__ ang)
{
  int idx = blockIdx.x * 256 + threadIdx.x;
  if (idx >= NMAG) return;
  int b = idx / (NW * NFREQ);
  int rem = idx - b * (NW * NFREQ);
  int f = rem / NFREQ;
  int k = rem - f * NFREQ;
  u32 cnt = (u32)(b * (NFREQ * NW) + k * NW + f);
  u32 w0, w1;
  threefry2(0u, cnt, w0, w1);
  u32 bits = w0 ^ w1;
  float u = __uint_as_float((bits >> 9) | 0x3f800000u) - 1.0f;
  float th = __fmul_rn((float)6.283185307179586, u);
  double thd = (double)th;
  ang[idx] = make_float2((float)cos(thd), (float)sin(thd));
}

// ---------------- 512-pt FFT: radix-8^3 Stockham, ONE WAVE per transform ----------------
__device__ __forceinline__ float2 cadd2(float2 a, float2 b){ return make_float2(a.x+b.x, a.y+b.y); }
__device__ __forceinline__ float2 csub2(float2 a, float2 b){ return make_float2(a.x-b.x, a.y-b.y); }

template<bool INV>
__device__ __forceinline__ float2 twmul(float2 a, float2 w)
{
  float wy = INV ? -w.y : w.y;
  return make_float2(a.x*w.x - a.y*wy, a.x*wy + a.y*w.x);
}

template<bool INV>
__device__ __forceinline__ void bfly8(float2 x0, float2 x1, float2 x2, float2 x3,
                                      float2 x4, float2 x5, float2 x6, float2 x7,
                                      float2 &Y0, float2 &Y1, float2 &Y2, float2 &Y3,
                                      float2 &Y4, float2 &Y5, float2 &Y6, float2 &Y7)
{
  const float c = 0.70710678118654752440f;
  float2 u0 = cadd2(x0,x4), u1 = cadd2(x1,x5), u2 = cadd2(x2,x6), u3 = cadd2(x3,x7);
  float2 d0 = csub2(x0,x4), d1 = csub2(x1,x5), d2 = csub2(x2,x6), d3 = csub2(x3,x7);
  float2 w1, w2, w3;
  if (!INV) {
    w1 = make_float2(c*(d1.x + d1.y), c*(d1.y - d1.x));   // x w8^1 = (c,-c)
    w2 = make_float2(d2.y, -d2.x);                        // x (-i)
    w3 = make_float2(c*(d3.y - d3.x), -c*(d3.x + d3.y));  // x w8^3 = (-c,-c)
  } else {
    w1 = make_float2(c*(d1.x - d1.y), c*(d1.x + d1.y));   // x (c,c)
    w2 = make_float2(-d2.y, d2.x);                        // x (+i)
    w3 = make_float2(-c*(d3.x + d3.y), c*(d3.x - d3.y));  // x (-c,c)
  }
  float2 s0 = cadd2(u0,u2), s1 = cadd2(u1,u3), s2 = csub2(u0,u2);
  float2 e13 = csub2(u1,u3);
  float2 s3 = INV ? make_float2(-e13.y, e13.x) : make_float2(e13.y, -e13.x);
  float2 r0 = cadd2(d0,w2), r1 = cadd2(w1,w3), r2 = csub2(d0,w2);
  float2 e57 = csub2(w1,w3);
  float2 r3 = INV ? make_float2(-e57.y, e57.x) : make_float2(e57.y, -e57.x);
  Y0 = cadd2(s0,s1); Y4 = csub2(s0,s1);
  Y2 = cadd2(s2,s3); Y6 = csub2(s2,s3);
  Y1 = cadd2(r0,r1); Y5 = csub2(r0,r1);
  Y3 = cadd2(r2,r3); Y7 = csub2(r2,r3);
}

// stage 0: inputs in registers, twiddle base = t, write slots 8t+k
template<bool INV>
__device__ __forceinline__ void stage0_regs(float2* __restrict__ A, const float2* __restrict__ tw, int t,
    float2 x0, float2 x1, float2 x2, float2 x3, float2 x4, float2 x5, float2 x6, float2 x7)
{
  float2 Y0,Y1,Y2,Y3,Y4,Y5,Y6,Y7;
  bfly8<INV>(x0,x1,x2,x3,x4,x5,x6,x7, Y0,Y1,Y2,Y3,Y4,Y5,Y6,Y7);
  int ob = 8 * t;
  A[SL(ob + 0)] = Y0;
  A[SL(ob + 1)] = twmul<INV>(Y1, tw[t]);
  A[SL(ob + 2)] = twmul<INV>(Y2, tw[2 * t]);
  A[SL(ob + 3)] = twmul<INV>(Y3, tw[3 * t]);
  A[SL(ob + 4)] = twmul<INV>(Y4, tw[4 * t]);
  A[SL(ob + 5)] = twmul<INV>(Y5, tw[5 * t]);
  A[SL(ob + 6)] = twmul<INV>(Y6, tw[6 * t]);
  A[SL(ob + 7)] = twmul<INV>(Y7, tw[7 * t]);
}

// stage 1 (L=8): in-place LDS->LDS, twiddle base = 8p, write slots q+64p+8k
template<bool INV>
__device__ __forceinline__ void stage_mid(float2* __restrict__ A, const float2* __restrict__ tw, int t)
{
  float2 x0 = A[SL(t)],       x1 = A[SL(t + 64)],  x2 = A[SL(t + 128)], x3 = A[SL(t + 192)];
  float2 x4 = A[SL(t + 256)], x5 = A[SL(t + 320)], x6 = A[SL(t + 384)], x7 = A[SL(t + 448)];
  float2 Y0,Y1,Y2,Y3,Y4,Y5,Y6,Y7;
  bfly8<INV>(x0,x1,x2,x3,x4,x5,x6,x7, Y0,Y1,Y2,Y3,Y4,Y5,Y6,Y7);
  WAVEFENCE();
  int p = t >> 3, q = t & 7;
  int base = 8 * p;
  int ob = q + 64 * p;
  A[SL(ob)]      = Y0;
  A[SL(ob + 8)]  = twmul<INV>(Y1, tw[base]);
  A[SL(ob + 16)] = twmul<INV>(Y2, tw[2 * base]);
  A[SL(ob + 24)] = twmul<INV>(Y3, tw[3 * base]);
  A[SL(ob + 32)] = twmul<INV>(Y4, tw[4 * base]);
  A[SL(ob + 40)] = twmul<INV>(Y5, tw[5 * base]);
  A[SL(ob + 48)] = twmul<INV>(Y6, tw[6 * base]);
  A[SL(ob + 56)] = twmul<INV>(Y7, tw[7 * base]);
}

// stage 2 (L=64, base=0): lane-local in-place, result natural order A[t+64k]
template<bool INV>
__device__ __forceinline__ void stage_last_lds(float2* __restrict__ A, int t)
{
  float2 x0 = A[SL(t)],       x1 = A[SL(t + 64)],  x2 = A[SL(t + 128)], x3 = A[SL(t + 192)];
  float2 x4 = A[SL(t + 256)], x5 = A[SL(t + 320)], x6 = A[SL(t + 384)], x7 = A[SL(t + 448)];
  float2 Y0,Y1,Y2,Y3,Y4,Y5,Y6,Y7;
  bfly8<INV>(x0,x1,x2,x3,x4,x5,x6,x7, Y0,Y1,Y2,Y3,Y4,Y5,Y6,Y7);
  WAVEFENCE();
  A[SL(t)]       = Y0; A[SL(t + 64)]  = Y1; A[SL(t + 128)] = Y2; A[SL(t + 192)] = Y3;
  A[SL(t + 256)] = Y4; A[SL(t + 320)] = Y5; A[SL(t + 384)] = Y6; A[SL(t + 448)] = Y7;
}

// stage 2 -> registers (inverse tail): Yk = time point t+64k
template<bool INV>
__device__ __forceinline__ void stage_last_regs(const float2* __restrict__ A, int t,
    float2 &Y0, float2 &Y1, float2 &Y2, float2 &Y3, float2 &Y4, float2 &Y5, float2 &Y6, float2 &Y7)
{
  float2 x0 = A[SL(t)],       x1 = A[SL(t + 64)],  x2 = A[SL(t + 128)], x3 = A[SL(t + 192)];
  float2 x4 = A[SL(t + 256)], x5 = A[SL(t + 320)], x6 = A[SL(t + 384)], x7 = A[SL(t + 448)];
  bfly8<INV>(x0,x1,x2,x3,x4,x5,x6,x7, Y0,Y1,Y2,Y3,Y4,Y5,Y6,Y7);
}

// momentum phase update for one bin; writes angL (slot-mapped) and tprev (f64 rfft combine)
__device__ __forceinline__ void upd_bin(float2* __restrict__ prow, float2* __restrict__ A,
                                        int k, double rx, double ry, float cf)
{
  float rxf = (float)rx, ryf = (float)ry;
  float2 pv = prow[k];
  float ax = __fsub_rn(rxf, __fmul_rn(pv.x, cf));
  float ay = __fsub_rn(ryf, __fmul_rn(pv.y, cf));
  double dx = (double)ax, dy = (double)ay;
  float d = (float)sqrt(dx * dx + dy * dy);
  float d2 = __fadd_rn(d, 1e-16f);
  float inv = __fdiv_rn(1.0f, d2);
  int slot = (k == 512) ? (WSL - 1) : SL(k);
  A[slot] = make_float2(__fmul_rn(ax, inv), __fmul_rn(ay, inv));
  prow[k] = make_float2(rxf, ryf);
}

// ---------------- initial ISTFT: wave-per-frame ----------------
__global__ __launch_bounds__(256) void k_istft(const float* __restrict__ mag, const float2* __restrict__ ang,
                                               float* __restrict__ frames,
                                               const float2* __restrict__ tw512f,
                                               const double2* __restrict__ twh,
                                               const float* __restrict__ win)
{
  __shared__ float2 ldsA[4 * WSL];
  __shared__ float2 twl[512];
  int tid = threadIdx.x;
  for (int i = tid; i < 512; i += 256) twl[i] = tw512f[i];
  __syncthreads();

  int wv = tid >> 6;
  int t  = tid & 63;
  int bf = (blockIdx.x << 2) + wv;
  float2* A = ldsA + wv * WSL;
  const float*  mrow = mag + bf * NFREQ;
  const float2* arow = ang + bf * NFREQ;

  // Hermitian pack straight into registers (points k = t + 64j), f64 combine
  float2 z0, z1, z2, z3, z4, z5, z6, z7;
#define PACKG(j, zj) { \
    int k = t + 64 * j; \
    if (k == 0) { \
      float m1 = mrow[0];   float2 a1 = arow[0]; \
      float m2 = mrow[512]; float2 a2 = arow[512]; \
      float S1x = __fmul_rn(m1, a1.x); \
      float S2x = __fmul_rn(m2, a2.x); \
      zj = make_float2((float)(0.5 * ((double)S1x + (double)S2x)), \
                       (float)(0.5 * ((double)S1x - (double)S2x))); \
    } else { \
      int k2 = 512 - k; \
      float m1 = mrow[k];  float2 a1 = arow[k]; \
      float m2 = mrow[k2]; float2 a2 = arow[k2]; \
      float S1x = __fmul_rn(m1, a1.x), S1y = __fmul_rn(m1, a1.y); \
      float S2x = __fmul_rn(m2, a2.x), S2y = __fmul_rn(m2, a2.y); \
      double Xex = 0.5 * ((double)S1x + (double)S2x); \
      double Xey = 0.5 * ((double)S1y - (double)S2y); \
      double Dx  = 0.5 * ((double)S1x - (double)S2x); \
      double Dy  = 0.5 * ((double)S1y + (double)S2y); \
      double2 w = twh[k]; \
      double ux = w.x * Dx + w.y * Dy; \
      double uy = w.x * Dy - w.y * Dx; \
      zj = make_float2((float)(Xex - uy), (float)(Xey + ux)); \
    } }
  PACKG(0, z0) PACKG(1, z1) PACKG(2, z2) PACKG(3, z3)
  PACKG(4, z4) PACKG(5, z5) PACKG(6, z6) PACKG(7, z7)

  stage0_regs<true>(A, twl, t, z0, z1, z2, z3, z4, z5, z6, z7);
  WAVEFENCE();
  stage_mid<true>(A, twl, t);
  WAVEFENCE();
  float2 y0, y1, y2, y3, y4, y5, y6, y7;
  stage_last_regs<true>(A, t, y0, y1, y2, y3, y4, y5, y6, y7);

  const float sc = 1.0f / 512.0f;
  const float2* win2 = (const float2*)win;
  float2* frow2 = (float2*)(frames + bf * NFFT);
#define STOREF(k, yk) { int m = t + 64 * k; float2 wv2 = win2[m]; \
    frow2[m] = make_float2(__fmul_rn(__fmul_rn(yk.x, sc), wv2.x), \
                           __fmul_rn(__fmul_rn(yk.y, sc), wv2.y)); }
  STOREF(0, y0) STOREF(1, y1) STOREF(2, y2) STOREF(3, y3)
  STOREF(4, y4) STOREF(5, y5) STOREF(6, y6) STOREF(7, y7)
}

// f32 OLA sample at wsq-coordinate j (R5-exact: divide by wsq)
__device__ __forceinline__ float sig_sample(const float* __restrict__ fb, const float* __restrict__ wsq, int j)
{
  int gmax = j >> 8; if (gmax > NW - 1) gmax = NW - 1;
  int gmin = (j >= NFFT) ? ((j - (NFFT - 1) + 255) >> 8) : 0;
  float acc = 0.f;
  for (int g = gmin; g <= gmax; ++g)
    acc = __fadd_rn(acc, fb[g * NFFT + (j - (g << 8))]);
  float wv = wsq[j];
  return __fdiv_rn(acc, wv > 1e-11f ? wv : 1.0f);
}

// ---------------- per-iteration: OLA + reflect-pad -> xp, 4 samples/thread (bit-identical ops) ----------------
__global__ __launch_bounds__(256) void k_sig(const float* __restrict__ frames, const float* __restrict__ wsq,
                                             float* __restrict__ xp)
{
  int idx = blockIdx.x * 256 + threadIdx.x;   // < BATCH*TOTAL_LEN/4
  int b  = idx / (TOTAL_LEN / 4);
  int j4 = (idx - b * (TOTAL_LEN / 4)) << 2;
  const float* fb = frames + b * (NW * NFFT);
  float4 v;
  float* vp = (float*)&v;
#pragma unroll
  for (int u = 0; u < 4; ++u) {
    int j = j4 + u;
    int n = j - 512;
    if (n < 0) n = -n;
    if (n >= SIGLEN) n = 2 * SIGLEN - 2 - n;
    vp[u] = sig_sample(fb, wsq, n + 512);
  }
  *(float4*)(xp + b * TOTAL_LEN + j4) = v;
}

// ---------------- FUSED: stft + momentum phase + istft, wave-per-frame (R5-exact numerics) ----------------
__global__ __launch_bounds__(256) void k_fused(const float* __restrict__ xp,
                                               const float* __restrict__ win,
                                               const float2* __restrict__ tw512f,
                                               const double2* __restrict__ twh,
                                               const float* __restrict__ mag,
                                               float2* __restrict__ tprev,
                                               float* __restrict__ frames)
{
  __shared__ float2 ldsA[4 * WSL];
  __shared__ float2 twl[512];
  int tid = threadIdx.x;
  for (int i = tid; i < 512; i += 256) twl[i] = tw512f[i];
  __syncthreads();

  int wv = tid >> 6;
  int t  = tid & 63;
  int bf = (blockIdx.x << 2) + wv;
  int b = bf >> 9;
  int f = bf & (NW - 1);
  float2* A = ldsA + wv * WSL;
  const float2* win2 = (const float2*)win;

  // ---- forward: windowed pack from global straight into stage 0 ----
  const float2* xrow2 = (const float2*)(xp + b * TOTAL_LEN + f * HOP);
  float2 x0, x1, x2, x3, x4, x5, x6, x7;
#define LOADX(j, xj) { float2 xv = xrow2[t + 64 * j]; float2 wv2 = win2[t + 64 * j]; \
    xj = make_float2(__fmul_rn(xv.x, wv2.x), __fmul_rn(xv.y, wv2.y)); }
  LOADX(0, x0) LOADX(1, x1) LOADX(2, x2) LOADX(3, x3)
  LOADX(4, x4) LOADX(5, x5) LOADX(6, x6) LOADX(7, x7)
  stage0_regs<false>(A, twl, t, x0, x1, x2, x3, x4, x5, x6, x7);
  WAVEFENCE();
  stage_mid<false>(A, twl, t);
  WAVEFENCE();
  stage_last_lds<false>(A, t);   // spectrum Z[k] at A[SL(k)], natural order
  WAVEFENCE();

  // ---- unpack rfft pairs (k, 512-k) + momentum update (f64 combine); angL overlays A ----
  float2* prow = tprev + bf * NFREQ;
  const float cf = (float)(0.99 / 1.99);
#pragma unroll
  for (int j = 0; j < 4; ++j) {
    int k = t + 64 * j;
    if (k == 0) {
      float2 Z0 = A[SL(0)];
      double rx0 = (double)Z0.x + (double)Z0.y;
      double rx5 = (double)Z0.x - (double)Z0.y;
      upd_bin(prow, A, 0,   rx0, 0.0, cf);
      upd_bin(prow, A, 512, rx5, 0.0, cf);
    } else {
      int kc = 512 - k;
      float2 Zk = A[SL(k)];
      float2 Zc = A[SL(kc)];
      double Xex = 0.5 * ((double)Zk.x + (double)Zc.x);
      double Xey = 0.5 * ((double)Zk.y - (double)Zc.y);
      double Gx  = 0.5 * ((double)Zk.x - (double)Zc.x);
      double Gy  = 0.5 * ((double)Zk.y + (double)Zc.y);
      double2 w = twh[k];
      double P = w.x * Gy + w.y * Gx;
      double Q = w.y * Gy - w.x * Gx;
      upd_bin(prow, A, k,  Xex + P, Xey + Q, cf);
      upd_bin(prow, A, kc, Xex - P, Q - Xey, cf);
    }
  }
  if (t == 0) {                      // self-paired bin k = 256
    float2 Zk = A[SL(256)];
    double Xex = 0.5 * ((double)Zk.x + (double)Zk.x);
    double Gy  = 0.5 * ((double)Zk.y + (double)Zk.y);
    double2 w = twh[256];
    double P = w.x * Gy;
    double Q = w.y * Gy;
    upd_bin(prow, A, 256, Xex + P, Q, cf);
  }
  WAVEFENCE();   // angL writes complete before PACKL reads (cross-lane)

  // ---- inverse: Hermitian pack mag*angL (from LDS) into registers (f64 combine), then 3 stages ----
  const float* mrow = mag + bf * NFREQ;
  float2 z0, z1, z2, z3, z4, z5, z6, z7;
#define PACKL(j, zj) { \
    int k = t + 64 * j; \
    if (k == 0) { \
      float m1 = mrow[0];   float2 a1 = A[SL(0)]; \
      float m2 = mrow[512]; float2 a2 = A[WSL - 1]; \
      float S1x = __fmul_rn(m1, a1.x); \
      float S2x = __fmul_rn(m2, a2.x); \
      zj = make_float2((float)(0.5 * ((double)S1x + (double)S2x)), \
                       (float)(0.5 * ((double)S1x - (double)S2x))); \
    } else { \
      int k2 = 512 - k; \
      float m1 = mrow[k];  float2 a1 = A[SL(k)]; \
      float m2 = mrow[k2]; float2 a2 = A[SL(k2)]; \
      float S1x = __fmul_rn(m1, a1.x), S1y = __fmul_rn(m1, a1.y); \
      float S2x = __fmul_rn(m2, a2.x), S2y = __fmul_rn(m2, a2.y); \
      double Xex = 0.5 * ((double)S1x + (double)S2x); \
      double Xey = 0.5 * ((double)S1y - (double)S2y); \
      double Dx  = 0.5 * ((double)S1x - (double)S2x); \
      double Dy  = 0.5 * ((double)S1y + (double)S2y); \
      double2 w = twh[k]; \
      double ux = w.x * Dx + w.y * Dy; \
      double uy = w.x * Dy - w.y * Dx; \
      zj = make_float2((float)(Xex - uy), (float)(Xey + ux)); \
    } }
  PACKL(0, z0) PACKL(1, z1) PACKL(2, z2) PACKL(3, z3)
  PACKL(4, z4) PACKL(5, z5) PACKL(6, z6) PACKL(7, z7)
  WAVEFENCE();   // all PACKL reads issued before stage0 overwrites A (cross-lane)

  stage0_regs<true>(A, twl, t, z0, z1, z2, z3, z4, z5, z6, z7);
  WAVEFENCE();
  stage_mid<true>(A, twl, t);
  WAVEFENCE();
  float2 y0, y1, y2, y3, y4, y5, y6, y7;
  stage_last_regs<true>(A, t, y0, y1, y2, y3, y4, y5, y6, y7);

  const float sc = 1.0f / 512.0f;
  float2* frow2 = (float2*)(frames + bf * NFFT);
  STOREF(0, y0) STOREF(1, y1) STOREF(2, y2) STOREF(3, y3)
  STOREF(4, y4) STOREF(5, y5) STOREF(6, y6) STOREF(7, y7)
}

// ---------------- final OLA -> audio f32 + per-block |max| ----------------
__global__ __launch_bounds__(256) void k_ola(const float* __restrict__ frames, const float* __restrict__ wsq,
                                             float* __restrict__ audio, float* __restrict__ partial)
{
  int idx = blockIdx.x * 256 + threadIdx.x;
  int b  = idx >> 17;
  int nn = idx & (NSAMP - 1);
  float v = 0.f;
  if (nn < SIGLEN)
    v = sig_sample(frames + b * (NW * NFFT), wsq, nn + 512);
  audio[idx] = v;
  __shared__ float red[256];
  red[threadIdx.x] = fabsf(v);
  __syncthreads();
  for (int s = 128; s > 0; s >>= 1) {
    if (threadIdx.x < s) red[threadIdx.x] = fmaxf(red[threadIdx.x], red[threadIdx.x + s]);
    __syncthreads();
  }
  if (threadIdx.x == 0) partial[blockIdx.x] = red[0];
}

constexpr int OLA_BLK_PER_B = NSAMP / 256;   // 512

__global__ __launch_bounds__(256) void k_max2(const float* __restrict__ partial, float* __restrict__ maxbuf)
{
  int b = blockIdx.x;
  float m = 0.f;
  for (int i = threadIdx.x; i < OLA_BLK_PER_B; i += 256)
    m = fmaxf(m, partial[b * OLA_BLK_PER_B + i]);
  __shared__ float red[256];
  red[threadIdx.x] = m;
  __syncthreads();
  for (int s = 128; s > 0; s >>= 1) {
    if (threadIdx.x < s) red[threadIdx.x] = fmaxf(red[threadIdx.x], red[threadIdx.x + s]);
    __syncthreads();
  }
  if (threadIdx.x == 0) maxbuf[b] = red[0];
}

__global__ __launch_bounds__(256) void k_norm(const float* __restrict__ audio, const float* __restrict__ maxbuf,
                                              float* __restrict__ out)
{
  int idx = blockIdx.x * 256 + threadIdx.x;
  int b = idx >> 17;
  float m = fmaxf(maxbuf[b], 1e-8f);
  out[idx] = __fmul_rn(__fdiv_rn(audio[idx], m), 0.9f);
}

extern "C" void kernel_launch(void* const* d_in, const int* in_sizes, int n_in,
                              void* d_out, int out_size, void* d_ws, size_t ws_size,
                              hipStream_t stream)
{
  const float* params = (const float*)d_in[0];
  float* out   = (float*)d_out;
  float* audio_out = out;                   // BATCH*NSAMP
  float* fs        = out + BATCH * NSAMP;   // BATCH*FH*FW (full_spec output)

  float2*  tw512f = (float2*)d_ws;                         // 512 (4KB)
  double2* twh    = (double2*)(tw512f + 512);              // 512 (8KB, 16B aligned)
  float2*  ang    = (float2*)(twh + 512);                  // NMAG c64 (initial phases only)
  float2*  tprev  = ang + NMAG;                            // NMAG c64
  float*   frames = (float*)(tprev + NMAG);                // BATCH*NW*NFFT f32
  float*   mag    = frames + BATCH * NW * NFFT;            // NMAG f32
  float*   xp     = mag + NMAG;                            // BATCH*TOTAL_LEN f32 (16B aligned)
  float*   win    = xp + BATCH * TOTAL_LEN;                // NFFT
  float*   wsq    = win + NFFT;                            // TOTAL_LEN
  float*   audio32= wsq + TOTAL_LEN;                       // BATCH*NSAMP
  float*   maxbuf = audio32 + BATCH * NSAMP;               // BATCH
  float*   partial= maxbuf + BATCH;                        // BATCH*OLA_BLK_PER_B

  k_init<<<512, 256, 0, stream>>>(win, tw512f, twh, wsq, tprev);
  k_fullspec<<<(BATCH * FH * FW) / 256, 256, 0, stream>>>(params, fs);
  k_mag<<<(NMAG + 255) / 256, 256, 0, stream>>>(params, mag);
  k_phase<<<(NMAG + 255) / 256, 256, 0, stream>>>(ang);

  k_istft<<<BATCH * NW / 4, 256, 0, stream>>>(mag, (const float2*)ang, frames, tw512f, twh, win);
  for (int it = 0; it < NITER; ++it) {
    k_sig<<<(BATCH * TOTAL_LEN / 4) / 256, 256, 0, stream>>>(frames, wsq, xp);
    k_fused<<<BATCH * NW / 4, 256, 0, stream>>>(xp, win, tw512f, twh, mag, tprev, frames);
  }
  k_ola<<<(BATCH * NSAMP) / 256, 256, 0, stream>>>(frames, wsq, audio32, partial);
  k_max2<<<BATCH, 256, 0, stream>>>(partial, maxbuf);
  k_norm<<<(BATCH * NSAMP) / 256, 256, 0, stream>>>(audio32, maxbuf, audio_out);
}

// Round 12
// 927.595 us; speedup vs baseline: 3.4046x; 1.0416x over previous
//
#include <hip/hip_runtime.h>

typedef unsigned int u32;

constexpr int BATCH = 8;
constexpr int GH = 32, GW = 64;
constexpr int FH = 128, FW = 512;
constexpr int NFFT = 1024;
constexpr int HOP = 256;
constexpr int NFREQ = 513;
constexpr int NW = 512;                       // frames per batch
constexpr int SIGLEN = HOP * (NW - 1);        // 130816
constexpr int TOTAL_LEN = NFFT + HOP*(NW-1);  // 131840
constexpr int NITER = 32;
constexpr int NSAMP = 131072;
constexpr int NMAG = BATCH * NW * NFREQ;      // 2101248

// LDS index padding (9/8 stride)
#define SL(i) ((i) + ((i) >> 3))
constexpr int WSL = 576;    // per-wave LDS slots: SL(511)=574, slot 575 = bin-512 home

#define WAVEFENCE() __builtin_amdgcn_wave_barrier()

// ---------------- Threefry-2x32-20, partitionable path (key = (0,1)) ----------------
__device__ __forceinline__ void tf_round(u32 &x0, u32 &x1, int r) {
  x0 += x1;
  x1 = (x1 << r) | (x1 >> (32 - r));
  x1 ^= x0;
}

__device__ __forceinline__ void threefry2(u32 c0, u32 c1, u32 &o0, u32 &o1) {
  const u32 k0 = 0u, k1 = 1u;
  const u32 k2 = 0x1BD11BDAu ^ k0 ^ k1;
  u32 x0 = c0 + k0, x1 = c1 + k1;
  tf_round(x0, x1, 13); tf_round(x0, x1, 15); tf_round(x0, x1, 26); tf_round(x0, x1, 6);
  x0 += k1; x1 += k2 + 1u;
  tf_round(x0, x1, 17); tf_round(x0, x1, 29); tf_round(x0, x1, 16); tf_round(x0, x1, 24);
  x0 += k2; x1 += k0 + 2u;
  tf_round(x0, x1, 13); tf_round(x0, x1, 15); tf_round(x0, x1, 26); tf_round(x0, x1, 6);
  x0 += k0; x1 += k1 + 3u;
  tf_round(x0, x1, 17); tf_round(x0, x1, 29); tf_round(x0, x1, 16); tf_round(x0, x1, 24);
  x0 += k1; x1 += k2 + 4u;
  tf_round(x0, x1, 13); tf_round(x0, x1, 15); tf_round(x0, x1, 26); tf_round(x0, x1, 6);
  x0 += k2; x1 += k0 + 5u;
  o0 = x0; o1 = x1;
}

// ---------------- init ----------------
__global__ __launch_bounds__(256) void k_init(float* __restrict__ win,
                                              float2* __restrict__ tw512f, double2* __restrict__ twh,
                                              float* __restrict__ wsq,
                                              float2* __restrict__ tprev)
{
  int idx = blockIdx.x * 256 + threadIdx.x;
  int stride = gridDim.x * 256;
  const double PI2 = 6.283185307179586476925286766559;
  for (int t = idx; t < NFFT; t += stride)
    win[t] = (float)(0.5 * (1.0 - cos(PI2 * (double)t / 1024.0)));  // _WIN f32
  for (int k = idx; k < 512; k += stride) {
    double th = -PI2 * (double)k / 512.0;
    tw512f[k] = make_float2((float)cos(th), (float)sin(th));  // e^{-2pi i k/512}
    double th2 = -PI2 * (double)k / 1024.0;
    double2 v2; v2.x = cos(th2); v2.y = sin(th2);
    twh[k] = v2;                                      // e^{-2pi i k/1024} (f64 boundary)
  }
  for (int j = idx; j < TOTAL_LEN; j += stride) {
    int gmax = j >> 8; if (gmax > NW - 1) gmax = NW - 1;
    int gmin = (j >= NFFT) ? ((j - (NFFT - 1) + 255) >> 8) : 0;
    float acc = 0.f;
    for (int g = gmin; g <= gmax; ++g) {
      float w = (float)(0.5 * (1.0 - cos(PI2 * (double)(j - (g << 8)) / 1024.0)));
      acc = __fadd_rn(acc, __fmul_rn(w, w));
    }
    wsq[j] = acc;
  }
  for (int i = idx; i < NMAG; i += stride)
    tprev[i] = make_float2(0.f, 0.f);
}

// ---------------- jax.image.resize bilinear ----------------
__device__ __forceinline__ void lin_taps(float sf, int in, int &i0, int &i1, float &w0, float &w1)
{
  if (sf <= 0.0f)                  { i0 = 0;      i1 = 0;      w0 = 1.0f; w1 = 0.0f; return; }
  if (sf >= (float)(in - 1))       { i0 = in - 1; i1 = in - 1; w0 = 1.0f; w1 = 0.0f; return; }
  i0 = (int)sf; i1 = i0 + 1;
  float x0 = __fsub_rn(sf, (float)i0);
  float a0 = __fsub_rn(1.0f, x0);
  float S  = __fadd_rn(a0, x0);
  w0 = __fdiv_rn(a0, S);
  w1 = __fdiv_rn(x0, S);
}

__device__ __forceinline__ float sf_H1(int H) {
  return __fadd_rn(__fmul_rn(__fadd_rn((float)H, 0.5f), 0.25f), -0.5f);
}
__device__ __forceinline__ float sf_W1(int W) {
  return __fadd_rn(__fmul_rn(__fadd_rn((float)W, 0.5f), 0.125f), -0.5f);
}
__device__ __forceinline__ float sf_H2(int K) {
  const float inv32 = (float)(1.0 / 4.0078125);
  return __fadd_rn(__fmul_rn(__fadd_rn((float)K, 0.5f), inv32), -0.5f);
}

__device__ __forceinline__ float fs_at(const float* __restrict__ pb, int H, int W)
{
  int r0, r1; float u0, u1;
  lin_taps(sf_H1(H), GH, r0, r1, u0, u1);
  int c0, c1; float v0, v1;
  lin_taps(sf_W1(W), GW, c0, c1, v0, v1);
  float t0 = __fmaf_rn(u1, pb[r1 * GW + c0], __fmul_rn(u0, pb[r0 * GW + c0]));
  float t1 = __fmaf_rn(u1, pb[r1 * GW + c1], __fmul_rn(u0, pb[r0 * GW + c1]));
  return __fmaf_rn(v1, t1, __fmul_rn(v0, t0));
}

__global__ __launch_bounds__(256) void k_fullspec(const float* __restrict__ p, float* __restrict__ fs)
{
  int idx = blockIdx.x * 256 + threadIdx.x;
  if (idx >= BATCH * FH * FW) return;
  int b = idx >> 16;
  int h = (idx >> 9) & (FH - 1);
  int w = idx & (FW - 1);
  fs[idx] = fs_at(p + b * (GH * GW), h, w);
}

__global__ __launch_bounds__(256) void k_mag(const float* __restrict__ p, float* __restrict__ mag)
{
  int idx = blockIdx.x * 256 + threadIdx.x;
  if (idx >= NMAG) return;
  int b = idx / (NW * NFREQ);
  int rem = idx - b * (NW * NFREQ);
  int f = rem / NFREQ;
  int k = rem - f * NFREQ;
  const float* pb = p + b * (GH * GW);
  int h0, h1; float wa, wb;
  lin_taps(sf_H2(k), FH, h0, h1, wa, wb);
  float fs0 = fs_at(pb, h0, f);
  float fs1 = fs_at(pb, h1, f);
  float P0 = __fmul_rn(__fmul_rn(fs0, fs0), 100.0f);
  float P1 = __fmul_rn(__fmul_rn(fs1, fs1), 100.0f);
  float lin = __fmaf_rn(wb, P1, __fmul_rn(wa, P0));
  mag[idx] = __fsqrt_rn(fmaxf(lin, 0.0f));
}

__global__ __launch_bounds__(256) void k_phase(float2* __restrict__ ang)
{
  int idx = blockIdx.x * 256 + threadIdx.x;
  if (idx >= NMAG) return;
  int b = idx / (NW * NFREQ);
  int rem = idx - b * (NW * NFREQ);
  int f = rem / NFREQ;
  int k = rem - f * NFREQ;
  u32 cnt = (u32)(b * (NFREQ * NW) + k * NW + f);
  u32 w0, w1;
  threefry2(0u, cnt, w0, w1);
  u32 bits = w0 ^ w1;
  float u = __uint_as_float((bits >> 9) | 0x3f800000u) - 1.0f;
  float th = __fmul_rn((float)6.283185307179586, u);
  double thd = (double)th;
  ang[idx] = make_float2((float)cos(thd), (float)sin(thd));
}

// ---------------- 512-pt FFT: radix-8^3 Stockham, ONE WAVE per transform ----------------
__device__ __forceinline__ float2 cadd2(float2 a, float2 b){ return make_float2(a.x+b.x, a.y+b.y); }
__device__ __forceinline__ float2 csub2(float2 a, float2 b){ return make_float2(a.x-b.x, a.y-b.y); }

template<bool INV>
__device__ __forceinline__ float2 twmul(float2 a, float2 w)
{
  float wy = INV ? -w.y : w.y;
  return make_float2(a.x*w.x - a.y*wy, a.x*wy + a.y*w.x);
}

template<bool INV>
__device__ __forceinline__ void bfly8(float2 x0, float2 x1, float2 x2, float2 x3,
                                      float2 x4, float2 x5, float2 x6, float2 x7,
                                      float2 &Y0, float2 &Y1, float2 &Y2, float2 &Y3,
                                      float2 &Y4, float2 &Y5, float2 &Y6, float2 &Y7)
{
  const float c = 0.70710678118654752440f;
  float2 u0 = cadd2(x0,x4), u1 = cadd2(x1,x5), u2 = cadd2(x2,x6), u3 = cadd2(x3,x7);
  float2 d0 = csub2(x0,x4), d1 = csub2(x1,x5), d2 = csub2(x2,x6), d3 = csub2(x3,x7);
  float2 w1, w2, w3;
  if (!INV) {
    w1 = make_float2(c*(d1.x + d1.y), c*(d1.y - d1.x));   // x w8^1 = (c,-c)
    w2 = make_float2(d2.y, -d2.x);                        // x (-i)
    w3 = make_float2(c*(d3.y - d3.x), -c*(d3.x + d3.y));  // x w8^3 = (-c,-c)
  } else {
    w1 = make_float2(c*(d1.x - d1.y), c*(d1.x + d1.y));   // x (c,c)
    w2 = make_float2(-d2.y, d2.x);                        // x (+i)
    w3 = make_float2(-c*(d3.x + d3.y), c*(d3.x - d3.y));  // x (-c,c)
  }
  float2 s0 = cadd2(u0,u2), s1 = cadd2(u1,u3), s2 = csub2(u0,u2);
  float2 e13 = csub2(u1,u3);
  float2 s3 = INV ? make_float2(-e13.y, e13.x) : make_float2(e13.y, -e13.x);
  float2 r0 = cadd2(d0,w2), r1 = cadd2(w1,w3), r2 = csub2(d0,w2);
  float2 e57 = csub2(w1,w3);
  float2 r3 = INV ? make_float2(-e57.y, e57.x) : make_float2(e57.y, -e57.x);
  Y0 = cadd2(s0,s1); Y4 = csub2(s0,s1);
  Y2 = cadd2(s2,s3); Y6 = csub2(s2,s3);
  Y1 = cadd2(r0,r1); Y5 = csub2(r0,r1);
  Y3 = cadd2(r2,r3); Y7 = csub2(r2,r3);
}

// stage 0: inputs in registers, twiddle base = t, write slots 8t+k
template<bool INV>
__device__ __forceinline__ void stage0_regs(float2* __restrict__ A, const float2* __restrict__ tw, int t,
    float2 x0, float2 x1, float2 x2, float2 x3, float2 x4, float2 x5, float2 x6, float2 x7)
{
  float2 Y0,Y1,Y2,Y3,Y4,Y5,Y6,Y7;
  bfly8<INV>(x0,x1,x2,x3,x4,x5,x6,x7, Y0,Y1,Y2,Y3,Y4,Y5,Y6,Y7);
  int ob = 8 * t;
  A[SL(ob + 0)] = Y0;
  A[SL(ob + 1)] = twmul<INV>(Y1, tw[t]);
  A[SL(ob + 2)] = twmul<INV>(Y2, tw[2 * t]);
  A[SL(ob + 3)] = twmul<INV>(Y3, tw[3 * t]);
  A[SL(ob + 4)] = twmul<INV>(Y4, tw[4 * t]);
  A[SL(ob + 5)] = twmul<INV>(Y5, tw[5 * t]);
  A[SL(ob + 6)] = twmul<INV>(Y6, tw[6 * t]);
  A[SL(ob + 7)] = twmul<INV>(Y7, tw[7 * t]);
}

// stage 1 (L=8): in-place LDS->LDS, twiddle base = 8p, write slots q+64p+8k
template<bool INV>
__device__ __forceinline__ void stage_mid(float2* __restrict__ A, const float2* __restrict__ tw, int t)
{
  float2 x0 = A[SL(t)],       x1 = A[SL(t + 64)],  x2 = A[SL(t + 128)], x3 = A[SL(t + 192)];
  float2 x4 = A[SL(t + 256)], x5 = A[SL(t + 320)], x6 = A[SL(t + 384)], x7 = A[SL(t + 448)];
  float2 Y0,Y1,Y2,Y3,Y4,Y5,Y6,Y7;
  bfly8<INV>(x0,x1,x2,x3,x4,x5,x6,x7, Y0,Y1,Y2,Y3,Y4,Y5,Y6,Y7);
  WAVEFENCE();
  int p = t >> 3, q = t & 7;
  int base = 8 * p;
  int ob = q + 64 * p;
  A[SL(ob)]      = Y0;
  A[SL(ob + 8)]  = twmul<INV>(Y1, tw[base]);
  A[SL(ob + 16)] = twmul<INV>(Y2, tw[2 * base]);
  A[SL(ob + 24)] = twmul<INV>(Y3, tw[3 * base]);
  A[SL(ob + 32)] = twmul<INV>(Y4, tw[4 * base]);
  A[SL(ob + 40)] = twmul<INV>(Y5, tw[5 * base]);
  A[SL(ob + 48)] = twmul<INV>(Y6, tw[6 * base]);
  A[SL(ob + 56)] = twmul<INV>(Y7, tw[7 * base]);
}

// stage 2 (L=64, base=0): lane-local in-place, result natural order A[t+64k]
template<bool INV>
__device__ __forceinline__ void stage_last_lds(float2* __restrict__ A, int t)
{
  float2 x0 = A[SL(t)],       x1 = A[SL(t + 64)],  x2 = A[SL(t + 128)], x3 = A[SL(t + 192)];
  float2 x4 = A[SL(t + 256)], x5 = A[SL(t + 320)], x6 = A[SL(t + 384)], x7 = A[SL(t + 448)];
  float2 Y0,Y1,Y2,Y3,Y4,Y5,Y6,Y7;
  bfly8<INV>(x0,x1,x2,x3,x4,x5,x6,x7, Y0,Y1,Y2,Y3,Y4,Y5,Y6,Y7);
  WAVEFENCE();
  A[SL(t)]       = Y0; A[SL(t + 64)]  = Y1; A[SL(t + 128)] = Y2; A[SL(t + 192)] = Y3;
  A[SL(t + 256)] = Y4; A[SL(t + 320)] = Y5; A[SL(t + 384)] = Y6; A[SL(t + 448)] = Y7;
}

// stage 2 -> registers (inverse tail): Yk = time point t+64k
template<bool INV>
__device__ __forceinline__ void stage_last_regs(const float2* __restrict__ A, int t,
    float2 &Y0, float2 &Y1, float2 &Y2, float2 &Y3, float2 &Y4, float2 &Y5, float2 &Y6, float2 &Y7)
{
  float2 x0 = A[SL(t)],       x1 = A[SL(t + 64)],  x2 = A[SL(t + 128)], x3 = A[SL(t + 192)];
  float2 x4 = A[SL(t + 256)], x5 = A[SL(t + 320)], x6 = A[SL(t + 384)], x7 = A[SL(t + 448)];
  bfly8<INV>(x0,x1,x2,x3,x4,x5,x6,x7, Y0,Y1,Y2,Y3,Y4,Y5,Y6,Y7);
}

// momentum phase update for one bin; writes angL (slot-mapped) and tprev (f64 rfft combine)
__device__ __forceinline__ void upd_bin(float2* __restrict__ prow, float2* __restrict__ A,
                                        int k, double rx, double ry, float cf)
{
  float rxf = (float)rx, ryf = (float)ry;
  float2 pv = prow[k];
  float ax = __fsub_rn(rxf, __fmul_rn(pv.x, cf));
  float ay = __fsub_rn(ryf, __fmul_rn(pv.y, cf));
  double dx = (double)ax, dy = (double)ay;
  float d = (float)sqrt(dx * dx + dy * dy);
  float d2 = __fadd_rn(d, 1e-16f);
  float inv = __fdiv_rn(1.0f, d2);
  int slot = (k == 512) ? (WSL - 1) : SL(k);
  A[slot] = make_float2(__fmul_rn(ax, inv), __fmul_rn(ay, inv));
  prow[k] = make_float2(rxf, ryf);
}

// ---------------- initial ISTFT: wave-per-frame ----------------
__global__ __launch_bounds__(256) void k_istft(const float* __restrict__ mag, const float2* __restrict__ ang,
                                               float* __restrict__ frames,
                                               const float2* __restrict__ tw512f,
                                               const double2* __restrict__ twh,
                                               const float* __restrict__ win)
{
  __shared__ float2 ldsA[4 * WSL];
  __shared__ float2 twl[512];
  int tid = threadIdx.x;
  for (int i = tid; i < 512; i += 256) twl[i] = tw512f[i];
  __syncthreads();

  int wv = tid >> 6;
  int t  = tid & 63;
  int bf = (blockIdx.x << 2) + wv;
  float2* A = ldsA + wv * WSL;
  const float*  mrow = mag + bf * NFREQ;
  const float2* arow = ang + bf * NFREQ;

  // Hermitian pack straight into registers (points k = t + 64j), f64 combine
  float2 z0, z1, z2, z3, z4, z5, z6, z7;
#define PACKG(j, zj) { \
    int k = t + 64 * j; \
    if (k == 0) { \
      float m1 = mrow[0];   float2 a1 = arow[0]; \
      float m2 = mrow[512]; float2 a2 = arow[512]; \
      float S1x = __fmul_rn(m1, a1.x); \
      float S2x = __fmul_rn(m2, a2.x); \
      zj = make_float2((float)(0.5 * ((double)S1x + (double)S2x)), \
                       (float)(0.5 * ((double)S1x - (double)S2x))); \
    } else { \
      int k2 = 512 - k; \
      float m1 = mrow[k];  float2 a1 = arow[k]; \
      float m2 = mrow[k2]; float2 a2 = arow[k2]; \
      float S1x = __fmul_rn(m1, a1.x), S1y = __fmul_rn(m1, a1.y); \
      float S2x = __fmul_rn(m2, a2.x), S2y = __fmul_rn(m2, a2.y); \
      double Xex = 0.5 * ((double)S1x + (double)S2x); \
      double Xey = 0.5 * ((double)S1y - (double)S2y); \
      double Dx  = 0.5 * ((double)S1x - (double)S2x); \
      double Dy  = 0.5 * ((double)S1y + (double)S2y); \
      double2 w = twh[k]; \
      double ux = w.x * Dx + w.y * Dy; \
      double uy = w.x * Dy - w.y * Dx; \
      zj = make_float2((float)(Xex - uy), (float)(Xey + ux)); \
    } }
  PACKG(0, z0) PACKG(1, z1) PACKG(2, z2) PACKG(3, z3)
  PACKG(4, z4) PACKG(5, z5) PACKG(6, z6) PACKG(7, z7)

  stage0_regs<true>(A, twl, t, z0, z1, z2, z3, z4, z5, z6, z7);
  WAVEFENCE();
  stage_mid<true>(A, twl, t);
  WAVEFENCE();
  float2 y0, y1, y2, y3, y4, y5, y6, y7;
  stage_last_regs<true>(A, t, y0, y1, y2, y3, y4, y5, y6, y7);

  const float sc = 1.0f / 512.0f;
  const float2* win2 = (const float2*)win;
  float2* frow2 = (float2*)(frames + bf * NFFT);
#define STOREF(k, yk) { int m = t + 64 * k; float2 wv2 = win2[m]; \
    frow2[m] = make_float2(__fmul_rn(__fmul_rn(yk.x, sc), wv2.x), \
                           __fmul_rn(__fmul_rn(yk.y, sc), wv2.y)); }
  STOREF(0, y0) STOREF(1, y1) STOREF(2, y2) STOREF(3, y3)
  STOREF(4, y4) STOREF(5, y5) STOREF(6, y6) STOREF(7, y7)
}

// f32 OLA sample at wsq-coordinate j (R5-exact: divide by wsq)
__device__ __forceinline__ float sig_sample(const float* __restrict__ fb, const float* __restrict__ wsq, int j)
{
  int gmax = j >> 8; if (gmax > NW - 1) gmax = NW - 1;
  int gmin = (j >= NFFT) ? ((j - (NFFT - 1) + 255) >> 8) : 0;
  float acc = 0.f;
  for (int g = gmin; g <= gmax; ++g)
    acc = __fadd_rn(acc, fb[g * NFFT + (j - (g << 8))]);
  float wv = wsq[j];
  return __fdiv_rn(acc, wv > 1e-11f ? wv : 1.0f);
}

// ---------------- per-iteration: OLA + reflect-pad -> xp (R5-exact, 1 sample/thread, coalesced) ----------------
__global__ __launch_bounds__(256) void k_sig(const float* __restrict__ frames, const float* __restrict__ wsq,
                                             float* __restrict__ xp)
{
  int idx = blockIdx.x * 256 + threadIdx.x;   // < BATCH*TOTAL_LEN
  int b = idx / TOTAL_LEN;
  int j = idx - b * TOTAL_LEN;
  int n = j - 512;
  if (n < 0) n = -n;
  if (n >= SIGLEN) n = 2 * SIGLEN - 2 - n;
  xp[idx] = sig_sample(frames + b * (NW * NFFT), wsq, n + 512);
}

// ---------------- FUSED: stft + momentum phase + istft, wave-per-frame (R5-exact numerics) ----------------
__global__ __launch_bounds__(256) void k_fused(const float* __restrict__ xp,
                                               const float* __restrict__ win,
                                               const float2* __restrict__ tw512f,
                                               const double2* __restrict__ twh,
                                               const float* __restrict__ mag,
                                               float2* __restrict__ tprev,
                                               float* __restrict__ frames)
{
  __shared__ float2 ldsA[4 * WSL];
  __shared__ float2 twl[512];
  int tid = threadIdx.x;
  for (int i = tid; i < 512; i += 256) twl[i] = tw512f[i];
  __syncthreads();

  int wv = tid >> 6;
  int t  = tid & 63;
  int bf = (blockIdx.x << 2) + wv;
  int b = bf >> 9;
  int f = bf & (NW - 1);
  float2* A = ldsA + wv * WSL;
  const float2* win2 = (const float2*)win;

  // ---- forward: windowed pack from global straight into stage 0 ----
  const float2* xrow2 = (const float2*)(xp + b * TOTAL_LEN + f * HOP);
  float2 x0, x1, x2, x3, x4, x5, x6, x7;
#define LOADX(j, xj) { float2 xv = xrow2[t + 64 * j]; float2 wv2 = win2[t + 64 * j]; \
    xj = make_float2(__fmul_rn(xv.x, wv2.x), __fmul_rn(xv.y, wv2.y)); }
  LOADX(0, x0) LOADX(1, x1) LOADX(2, x2) LOADX(3, x3)
  LOADX(4, x4) LOADX(5, x5) LOADX(6, x6) LOADX(7, x7)
  stage0_regs<false>(A, twl, t, x0, x1, x2, x3, x4, x5, x6, x7);
  WAVEFENCE();
  stage_mid<false>(A, twl, t);
  WAVEFENCE();
  stage_last_lds<false>(A, t);   // spectrum Z[k] at A[SL(k)], natural order
  WAVEFENCE();

  // ---- unpack rfft pairs (k, 512-k) + momentum update (f64 combine); angL overlays A ----
  float2* prow = tprev + bf * NFREQ;
  const float cf = (float)(0.99 / 1.99);
#pragma unroll
  for (int j = 0; j < 4; ++j) {
    int k = t + 64 * j;
    if (k == 0) {
      float2 Z0 = A[SL(0)];
      double rx0 = (double)Z0.x + (double)Z0.y;
      double rx5 = (double)Z0.x - (double)Z0.y;
      upd_bin(prow, A, 0,   rx0, 0.0, cf);
      upd_bin(prow, A, 512, rx5, 0.0, cf);
    } else {
      int kc = 512 - k;
      float2 Zk = A[SL(k)];
      float2 Zc = A[SL(kc)];
      double Xex = 0.5 * ((double)Zk.x + (double)Zc.x);
      double Xey = 0.5 * ((double)Zk.y - (double)Zc.y);
      double Gx  = 0.5 * ((double)Zk.x - (double)Zc.x);
      double Gy  = 0.5 * ((double)Zk.y + (double)Zc.y);
      double2 w = twh[k];
      double P = w.x * Gy + w.y * Gx;
      double Q = w.y * Gy - w.x * Gx;
      upd_bin(prow, A, k,  Xex + P, Xey + Q, cf);
      upd_bin(prow, A, kc, Xex - P, Q - Xey, cf);
    }
  }
  if (t == 0) {                      // self-paired bin k = 256
    float2 Zk = A[SL(256)];
    double Xex = 0.5 * ((double)Zk.x + (double)Zk.x);
    double Gy  = 0.5 * ((double)Zk.y + (double)Zk.y);
    double2 w = twh[256];
    double P = w.x * Gy;
    double Q = w.y * Gy;
    upd_bin(prow, A, 256, Xex + P, Q, cf);
  }
  WAVEFENCE();   // angL writes complete before PACKL reads (cross-lane)

  // ---- inverse: Hermitian pack mag*angL (from LDS) into registers (f64 combine), then 3 stages ----
  const float* mrow = mag + bf * NFREQ;
  float2 z0, z1, z2, z3, z4, z5, z6, z7;
#define PACKL(j, zj) { \
    int k = t + 64 * j; \
    if (k == 0) { \
      float m1 = mrow[0];   float2 a1 = A[SL(0)]; \
      float m2 = mrow[512]; float2 a2 = A[WSL - 1]; \
      float S1x = __fmul_rn(m1, a1.x); \
      float S2x = __fmul_rn(m2, a2.x); \
      zj = make_float2((float)(0.5 * ((double)S1x + (double)S2x)), \
                       (float)(0.5 * ((double)S1x - (double)S2x))); \
    } else { \
      int k2 = 512 - k; \
      float m1 = mrow[k];  float2 a1 = A[SL(k)]; \
      float m2 = mrow[k2]; float2 a2 = A[SL(k2)]; \
      float S1x = __fmul_rn(m1, a1.x), S1y = __fmul_rn(m1, a1.y); \
      float S2x = __fmul_rn(m2, a2.x), S2y = __fmul_rn(m2, a2.y); \
      double Xex = 0.5 * ((double)S1x + (double)S2x); \
      double Xey = 0.5 * ((double)S1y - (double)S2y); \
      double Dx  = 0.5 * ((double)S1x - (double)S2x); \
      double Dy  = 0.5 * ((double)S1y + (double)S2y); \
      double2 w = twh[k]; \
      double ux = w.x * Dx + w.y * Dy; \
      double uy = w.x * Dy - w.y * Dx; \
      zj = make_float2((float)(Xex - uy), (float)(Xey + ux)); \
    } }
  PACKL(0, z0) PACKL(1, z1) PACKL(2, z2) PACKL(3, z3)
  PACKL(4, z4) PACKL(5, z5) PACKL(6, z6) PACKL(7, z7)
  WAVEFENCE();   // all PACKL reads issued before stage0 overwrites A (cross-lane)

  stage0_regs<true>(A, twl, t, z0, z1, z2, z3, z4, z5, z6, z7);
  WAVEFENCE();
  stage_mid<true>(A, twl, t);
  WAVEFENCE();
  float2 y0, y1, y2, y3, y4, y5, y6, y7;
  stage_last_regs<true>(A, t, y0, y1, y2, y3, y4, y5, y6, y7);

  const float sc = 1.0f / 512.0f;
  float2* frow2 = (float2*)(frames + bf * NFFT);
  STOREF(0, y0) STOREF(1, y1) STOREF(2, y2) STOREF(3, y3)
  STOREF(4, y4) STOREF(5, y5) STOREF(6, y6) STOREF(7, y7)
}

// ---------------- final OLA -> audio f32 + per-block |max| ----------------
__global__ __launch_bounds__(256) void k_ola(const float* __restrict__ frames, const float* __restrict__ wsq,
                                             float* __restrict__ audio, float* __restrict__ partial)
{
  int idx = blockIdx.x * 256 + threadIdx.x;
  int b  = idx >> 17;
  int nn = idx & (NSAMP - 1);
  float v = 0.f;
  if (nn < SIGLEN)
    v = sig_sample(frames + b * (NW * NFFT), wsq, nn + 512);
  audio[idx] = v;
  __shared__ float red[256];
  red[threadIdx.x] = fabsf(v);
  __syncthreads();
  for (int s = 128; s > 0; s >>= 1) {
    if (threadIdx.x < s) red[threadIdx.x] = fmaxf(red[threadIdx.x], red[threadIdx.x + s]);
    __syncthreads();
  }
  if (threadIdx.x == 0) partial[blockIdx.x] = red[0];
}

constexpr int OLA_BLK_PER_B = NSAMP / 256;   // 512

__global__ __launch_bounds__(256) void k_max2(const float* __restrict__ partial, float* __restrict__ maxbuf)
{
  int b = blockIdx.x;
  float m = 0.f;
  for (int i = threadIdx.x; i < OLA_BLK_PER_B; i += 256)
    m = fmaxf(m, partial[b * OLA_BLK_PER_B + i]);
  __shared__ float red[256];
  red[threadIdx.x] = m;
  __syncthreads();
  for (int s = 128; s > 0; s >>= 1) {
    if (threadIdx.x < s) red[threadIdx.x] = fmaxf(red[threadIdx.x], red[threadIdx.x + s]);
    __syncthreads();
  }
  if (threadIdx.x == 0) maxbuf[b] = red[0];
}

__global__ __launch_bounds__(256) void k_norm(const float* __restrict__ audio, const float* __restrict__ maxbuf,
                                              float* __restrict__ out)
{
  int idx = blockIdx.x * 256 + threadIdx.x;
  int b = idx >> 17;
  float m = fmaxf(maxbuf[b], 1e-8f);
  out[idx] = __fmul_rn(__fdiv_rn(audio[idx], m), 0.9f);
}

extern "C" void kernel_launch(void* const* d_in, const int* in_sizes, int n_in,
                              void* d_out, int out_size, void* d_ws, size_t ws_size,
                              hipStream_t stream)
{
  const float* params = (const float*)d_in[0];
  float* out   = (float*)d_out;
  float* audio_out = out;                   // BATCH*NSAMP
  float* fs        = out + BATCH * NSAMP;   // BATCH*FH*FW (full_spec output)

  float2*  tw512f = (float2*)d_ws;                         // 512 (4KB)
  double2* twh    = (double2*)(tw512f + 512);              // 512 (8KB, 16B aligned)
  float2*  ang    = (float2*)(twh + 512);                  // NMAG c64 (initial phases only)
  float2*  tprev  = ang + NMAG;                            // NMAG c64
  float*   frames = (float*)(tprev + NMAG);                // BATCH*NW*NFFT f32
  float*   mag    = frames + BATCH * NW * NFFT;            // NMAG f32
  float*   xp     = mag + NMAG;                            // BATCH*TOTAL_LEN f32
  float*   win    = xp + BATCH * TOTAL_LEN;                // NFFT
  float*   wsq    = win + NFFT;                            // TOTAL_LEN
  float*   audio32= wsq + TOTAL_LEN;                       // BATCH*NSAMP
  float*   maxbuf = audio32 + BATCH * NSAMP;               // BATCH
  float*   partial= maxbuf + BATCH;                        // BATCH*OLA_BLK_PER_B

  k_init<<<512, 256, 0, stream>>>(win, tw512f, twh, wsq, tprev);
  k_fullspec<<<(BATCH * FH * FW) / 256, 256, 0, stream>>>(params, fs);
  k_mag<<<(NMAG + 255) / 256, 256, 0, stream>>>(params, mag);
  k_phase<<<(NMAG + 255) / 256, 256, 0, stream>>>(ang);

  k_istft<<<BATCH * NW / 4, 256, 0, stream>>>(mag, (const float2*)ang, frames, tw512f, twh, win);
  for (int it = 0; it < NITER; ++it) {
    k_sig<<<(BATCH * TOTAL_LEN) / 256, 256, 0, stream>>>(frames, wsq, xp);
    k_fused<<<BATCH * NW / 4, 256, 0, stream>>>(xp, win, tw512f, twh, mag, tprev, frames);
  }
  k_ola<<<(BATCH * NSAMP) / 256, 256, 0, stream>>>(frames, wsq, audio32, partial);
  k_max2<<<BATCH, 256, 0, stream>>>(partial, maxbuf);
  k_norm<<<(BATCH * NSAMP) / 256, 256, 0, stream>>>(audio32, maxbuf, audio_out);
}